// Round 2
// baseline (204.958 us; speedup 1.0000x reference)
//
#include <hip/hip_runtime.h>
#include <hip/hip_bf16.h>

// B=4, S=2048, D=1024, H=16, dk=64. M = B*S = 8192.
// All GEMMs: C[m,n] = sum_k A[m,k] * W[n,k]  (W row-major [out][in], "NT")

typedef __bf16 bf16x8 __attribute__((ext_vector_type(8)));
typedef __bf16 bf16x4 __attribute__((ext_vector_type(4)));
typedef float  f32x4  __attribute__((ext_vector_type(4)));
typedef float  f32x16 __attribute__((ext_vector_type(16)));
typedef unsigned int u32x4_t __attribute__((ext_vector_type(4)));

#define GLOBAL_AS __attribute__((address_space(1)))
#define LDS_AS    __attribute__((address_space(3)))

__device__ __forceinline__ void gload16(const void* g, void* l) {
    __builtin_amdgcn_global_load_lds((const GLOBAL_AS void*)g, (LDS_AS void*)l, 16, 0, 0);
}

__device__ __forceinline__ unsigned int cvtpk_bf16(float lo, float hi) {
    unsigned int r;
    asm("v_cvt_pk_bf16_f32 %0, %1, %2" : "=v"(r) : "v"(lo), "v"(hi));
    return r;
}

#define WAITVM6 asm volatile("s_waitcnt vmcnt(6)" ::: "memory")
#define WAITVM4 asm volatile("s_waitcnt vmcnt(4)" ::: "memory")
#define WAITVM0 asm volatile("s_waitcnt vmcnt(0)" ::: "memory")
#define SCHEDB  __builtin_amdgcn_sched_barrier(0)

// ---------------------------------------------------------------- cast kernel
__global__ __launch_bounds__(256) void cast_kernel(
    const float* __restrict__ x, const float* __restrict__ wq,
    const float* __restrict__ wk, const float* __restrict__ wv,
    const float* __restrict__ wo, __bf16* __restrict__ xb, __bf16* __restrict__ wb) {
    int bid = blockIdx.x;
    const float* src; __bf16* dst; int base;
    if (bid < 4096) {
        src = x; dst = xb; base = bid * 2048;
    } else {
        int r = bid - 4096; int wi = r >> 9;
        src = (wi == 0) ? wq : (wi == 1) ? wk : (wi == 2) ? wv : wo;
        dst = wb + wi * 1048576; base = (r & 511) * 2048;
    }
    int idx = base + threadIdx.x * 8;
    float4 a = *(const float4*)(src + idx);
    float4 b = *(const float4*)(src + idx + 4);
    bf16x8 o;
    o[0] = (__bf16)a.x; o[1] = (__bf16)a.y; o[2] = (__bf16)a.z; o[3] = (__bf16)a.w;
    o[4] = (__bf16)b.x; o[5] = (__bf16)b.y; o[6] = (__bf16)b.z; o[7] = (__bf16)b.w;
    *(bf16x8*)(dst + idx) = o;
}

// ---------------------------------------------------------------- fused QKV GEMM
// 128(M) x 256(N) tile, BK=64, 512 thr / 8 waves (2Mx4N), wave tile 64x64.
// Triple-buffered LDS (3 x 48KB), counted vmcnt(6) pipeline (T3+T4), XOR-swizzled
// LDS rows via pre-swizzled global_load_lds source (T2, both-sides), setprio (T5).
// Grid 768 = 64 mt x 12 nt, XCD-swizzled (768 % 8 == 0 -> bijective).
// nt 0-3 -> Qb (scaled, swapped-mfma epi); 4-7 -> Kb; 8-11 -> Vt[b][h][d][s].
__global__ __launch_bounds__(512, 2) void gemm_qkv_kernel(
    const __bf16* __restrict__ A, const __bf16* __restrict__ W,
    __bf16* __restrict__ Qb, __bf16* __restrict__ Kb, __bf16* __restrict__ Vt,
    float qscale) {
    __shared__ __align__(16) char lds[147456];  // 3 x (A 16KB + B 32KB)
    const int t = threadIdx.x;
    const int wid = t >> 6, lane = t & 63;
    const int g = lane >> 4, m = lane & 15;
    const int wm = wid >> 2, wn = wid & 3;
    const int bid = (blockIdx.x & 7) * 96 + (blockIdx.x >> 3);
    const int mt = bid / 12, nt = bid % 12;
    const int m0 = mt * 128, n0 = nt * 256;
    const bool isV = (n0 >= 2048);

    // --- staging: per-thread pre-swizzled global sources, linear LDS dest ---
    const __bf16* sA[2]; int dA[2];
#pragma unroll
    for (int i = 0; i < 2; ++i) {
        const int ci = i * 512 + t;
        const int row = ci >> 3;
        const int k8 = (ci & 7) ^ (row & 7);
        sA[i] = A + (size_t)(m0 + row) * 1024 + k8 * 8;
        dA[i] = ci * 16;
    }
    const __bf16* sB[4]; int dB[4];
#pragma unroll
    for (int i = 0; i < 4; ++i) {
        const int ci = i * 512 + t;
        const int row = ci >> 3;
        const int k8 = (ci & 7) ^ (row & 7);
        sB[i] = W + (size_t)(n0 + row) * 1024 + k8 * 8;
        dB[i] = ci * 16;
    }
    auto stage = [&](int kt, char* buf) {
        gload16(sA[0] + kt * 64, buf + dA[0]);
        gload16(sA[1] + kt * 64, buf + dA[1]);
        gload16(sB[0] + kt * 64, buf + 16384 + dB[0]);
        gload16(sB[1] + kt * 64, buf + 16384 + dB[1]);
        gload16(sB[2] + kt * 64, buf + 16384 + dB[2]);
        gload16(sB[3] + kt * 64, buf + 16384 + dB[3]);
    };

    // --- fragment read offsets (swizzle = ((row&7)<<4), row&7 == m&7) ---
    const int sw = (m & 7) << 4;
    const int offA = (wm * 64 + m) * 128 + ((g << 4) ^ sw);
    const int offB = (wn * 64 + m) * 128 + ((g << 4) ^ sw);

    // --- prologue: tiles 0,1 in flight; wait tile0 only ---
    stage(0, lds);
    stage(1, lds + 49152);
    WAITVM6;
    SCHEDB;
    __builtin_amdgcn_s_barrier();
    SCHEDB;

    f32x4 acc[4][4] = {};
    for (int kt = 0; kt < 16; ++kt) {
        char* cbuf = lds + (kt % 3) * 49152;
        if (kt < 14) stage(kt + 2, lds + ((kt + 2) % 3) * 49152);
        const char* bA = cbuf;
        const char* bB = cbuf + 16384;
        bf16x8 a0[4], b0[4], a1[4], b1[4];
#pragma unroll
        for (int i = 0; i < 4; ++i) {
            a0[i] = *(const bf16x8*)(bA + (offA + i * 2048));
            b0[i] = *(const bf16x8*)(bB + (offB + i * 2048));
            a1[i] = *(const bf16x8*)(bA + ((offA + i * 2048) ^ 64));
            b1[i] = *(const bf16x8*)(bB + ((offB + i * 2048) ^ 64));
        }
        __builtin_amdgcn_s_setprio(1);
        if (isV) {
#pragma unroll
            for (int mi = 0; mi < 4; ++mi)
#pragma unroll
                for (int ni = 0; ni < 4; ++ni)
                    acc[mi][ni] = __builtin_amdgcn_mfma_f32_16x16x32_bf16(a0[mi], b0[ni], acc[mi][ni], 0, 0, 0);
#pragma unroll
            for (int mi = 0; mi < 4; ++mi)
#pragma unroll
                for (int ni = 0; ni < 4; ++ni)
                    acc[mi][ni] = __builtin_amdgcn_mfma_f32_16x16x32_bf16(a1[mi], b1[ni], acc[mi][ni], 0, 0, 0);
        } else {
#pragma unroll
            for (int mi = 0; mi < 4; ++mi)
#pragma unroll
                for (int ni = 0; ni < 4; ++ni)
                    acc[mi][ni] = __builtin_amdgcn_mfma_f32_16x16x32_bf16(b0[ni], a0[mi], acc[mi][ni], 0, 0, 0);
#pragma unroll
            for (int mi = 0; mi < 4; ++mi)
#pragma unroll
                for (int ni = 0; ni < 4; ++ni)
                    acc[mi][ni] = __builtin_amdgcn_mfma_f32_16x16x32_bf16(b1[ni], a1[mi], acc[mi][ni], 0, 0, 0);
        }
        __builtin_amdgcn_s_setprio(0);
        if (kt < 14) { WAITVM6; }          // tile kt+1 staged; kt+2's 6 ops in flight
        else if (kt == 14) { WAITVM0; }    // tail: tile 15 staged
        if (kt < 15) {
            SCHEDB;
            __builtin_amdgcn_s_barrier();
            SCHEDB;
        }
    }

    if (isV) {
        const int bb = m0 >> 11;
        const int sb = (m0 & 2047) + wm * 64 + 4 * g;
        const int hbase = ((n0 - 2048) >> 6) + wn;
#pragma unroll
        for (int mi = 0; mi < 4; ++mi)
#pragma unroll
            for (int ni = 0; ni < 4; ++ni) {
                const int d = ni * 16 + m;
                bf16x4 pk;
                pk[0] = (__bf16)(acc[mi][ni][0]); pk[1] = (__bf16)(acc[mi][ni][1]);
                pk[2] = (__bf16)(acc[mi][ni][2]); pk[3] = (__bf16)(acc[mi][ni][3]);
                *(bf16x4*)(Vt + ((size_t)(bb * 16 + hbase) * 64 + d) * 2048 + sb + mi * 16) = pk;
            }
    } else {
        __bf16* C = (n0 < 1024) ? Qb : Kb;
        const float sc = (n0 < 1024) ? qscale : 1.f;
        const int cb = (n0 & 1023) + wn * 64 + 4 * g;
        const int row = m0 + wm * 64 + m;
#pragma unroll
        for (int mi = 0; mi < 4; ++mi)
#pragma unroll
            for (int ni = 0; ni < 4; ++ni) {
                bf16x4 pk;
                pk[0] = (__bf16)(acc[mi][ni][0] * sc); pk[1] = (__bf16)(acc[mi][ni][1] * sc);
                pk[2] = (__bf16)(acc[mi][ni][2] * sc); pk[3] = (__bf16)(acc[mi][ni][3] * sc);
                *(bf16x4*)(C + (size_t)(row + mi * 16) * 1024 + cb + ni * 16) = pk;
            }
    }
}

// ---------------------------------------------------------------- output GEMM (f32)
__global__ __launch_bounds__(512, 2) void gemm_out_kernel(
    const __bf16* __restrict__ A, const __bf16* __restrict__ W, float* __restrict__ out) {
    __shared__ __align__(16) char lds[147456];
    const int t = threadIdx.x;
    const int wid = t >> 6, lane = t & 63;
    const int g = lane >> 4, m = lane & 15;
    const int wm = wid >> 2, wn = wid & 3;
    const int bid = (blockIdx.x & 7) * 32 + (blockIdx.x >> 3);
    const int mt = bid >> 2, nt = bid & 3;
    const int m0 = mt * 128, n0 = nt * 256;

    const __bf16* sA[2]; int dA[2];
#pragma unroll
    for (int i = 0; i < 2; ++i) {
        const int ci = i * 512 + t;
        const int row = ci >> 3;
        const int k8 = (ci & 7) ^ (row & 7);
        sA[i] = A + (size_t)(m0 + row) * 1024 + k8 * 8;
        dA[i] = ci * 16;
    }
    const __bf16* sB[4]; int dB[4];
#pragma unroll
    for (int i = 0; i < 4; ++i) {
        const int ci = i * 512 + t;
        const int row = ci >> 3;
        const int k8 = (ci & 7) ^ (row & 7);
        sB[i] = W + (size_t)(n0 + row) * 1024 + k8 * 8;
        dB[i] = ci * 16;
    }
    auto stage = [&](int kt, char* buf) {
        gload16(sA[0] + kt * 64, buf + dA[0]);
        gload16(sA[1] + kt * 64, buf + dA[1]);
        gload16(sB[0] + kt * 64, buf + 16384 + dB[0]);
        gload16(sB[1] + kt * 64, buf + 16384 + dB[1]);
        gload16(sB[2] + kt * 64, buf + 16384 + dB[2]);
        gload16(sB[3] + kt * 64, buf + 16384 + dB[3]);
    };

    const int sw = (m & 7) << 4;
    const int offA = (wm * 64 + m) * 128 + ((g << 4) ^ sw);
    const int offB = (wn * 64 + m) * 128 + ((g << 4) ^ sw);

    stage(0, lds);
    stage(1, lds + 49152);
    WAITVM6;
    SCHEDB;
    __builtin_amdgcn_s_barrier();
    SCHEDB;

    f32x4 acc[4][4] = {};
    for (int kt = 0; kt < 16; ++kt) {
        char* cbuf = lds + (kt % 3) * 49152;
        if (kt < 14) stage(kt + 2, lds + ((kt + 2) % 3) * 49152);
        const char* bA = cbuf;
        const char* bB = cbuf + 16384;
        bf16x8 a0[4], b0[4], a1[4], b1[4];
#pragma unroll
        for (int i = 0; i < 4; ++i) {
            a0[i] = *(const bf16x8*)(bA + (offA + i * 2048));
            b0[i] = *(const bf16x8*)(bB + (offB + i * 2048));
            a1[i] = *(const bf16x8*)(bA + ((offA + i * 2048) ^ 64));
            b1[i] = *(const bf16x8*)(bB + ((offB + i * 2048) ^ 64));
        }
        __builtin_amdgcn_s_setprio(1);
#pragma unroll
        for (int mi = 0; mi < 4; ++mi)
#pragma unroll
            for (int ni = 0; ni < 4; ++ni)
                acc[mi][ni] = __builtin_amdgcn_mfma_f32_16x16x32_bf16(b0[ni], a0[mi], acc[mi][ni], 0, 0, 0);
#pragma unroll
        for (int mi = 0; mi < 4; ++mi)
#pragma unroll
            for (int ni = 0; ni < 4; ++ni)
                acc[mi][ni] = __builtin_amdgcn_mfma_f32_16x16x32_bf16(b1[ni], a1[mi], acc[mi][ni], 0, 0, 0);
        __builtin_amdgcn_s_setprio(0);
        if (kt < 14) { WAITVM6; }
        else if (kt == 14) { WAITVM0; }
        if (kt < 15) {
            SCHEDB;
            __builtin_amdgcn_s_barrier();
            SCHEDB;
        }
    }

    const int row = m0 + wm * 64 + m;
    const int col = n0 + wn * 64 + 4 * g;
#pragma unroll
    for (int mi = 0; mi < 4; ++mi)
#pragma unroll
        for (int ni = 0; ni < 4; ++ni)
            *(f32x4*)(out + (size_t)(row + mi * 16) * 1024 + col + ni * 16) = acc[mi][ni];
}

// ---------------------------------------------------------------- flash attention v6
// 4 waves / 256 threads per block sharing one K/V LDS double-buffer: block owns a
// 128-row Q panel (wave w -> rows q0+32w..+31), one shared kv-tile stream.
// 1024 blocks x 4 waves = 16 waves/CU (4/SIMD; LDS 4x32KB=128KB, VGPR<=128) --
// doubles occupancy vs v5 to feed the VALU pipe (softmax) from more waves.
// Causality: all waves run the block's nt tiles; mask when kv0+63 > q0w (covers
// diagonal + fully-masked trailing tiles; masked tiles take the skip path, p=0).
// Index map pairs strips (j, 15-j) across residency rounds for CU balance and
// keeps 8 bh per XCD (K+V 4MB = L2).
__global__ __launch_bounds__(256, 4) void attn_kernel(
    const __bf16* __restrict__ Qb, const __bf16* __restrict__ Kb,
    const __bf16* __restrict__ Vt, __bf16* __restrict__ Ob) {
    __shared__ __align__(16) char lds[32768];  // 2 bufs x (K 8KB + V 8KB)
    const int t = threadIdx.x;
    const int w = t >> 6, lane = t & 63;
    const int l31 = lane & 31, hi = lane >> 5;
    // launch idx x: xcd = x&7; p = x>>3; r = p>>5 (residency round), c = p&31;
    // strip = (r&1) ? 15-(c&15) : (c&15); bh_local = (c>>4) + 2r; bh = xcd | bh_local<<3
    const int x = blockIdx.x;
    const int p = x >> 3;
    const int r = p >> 5, c = p & 31, j = c & 15;
    const int strip = (r & 1) ? (15 - j) : j;
    const int bh = (x & 7) | (((c >> 4) + 2 * r) << 3);
    const size_t sbase = (size_t)(bh >> 4) * 2048;
    const int hoff = (bh & 15) * 64;

    const int q0w = strip * 128 + w * 32;
    const int nt = 2 * (strip + 1);
    const int q = q0w + l31;

    const char* Kbase = (const char*)Kb + (sbase * 1024 + hoff) * 2;
    const char* Vbase = (const char*)Vt + (size_t)bh * 262144;
    const int srow = lane >> 3;
    const int scol = ((lane & 7) ^ srow) << 4;  // pre-swizzled source slot
    const int sw = (l31 & 7) << 4;              // read-side swizzle
    int colx[4];
#pragma unroll
    for (int i = 0; i < 4; ++i) colx[i] = (32 * i + 16 * hi) ^ sw;

    // stage one K+V tile (16 chunks of 1KB) split across 4 waves: 4 gload16/wave
    auto stage = [&](int kv0, char* lK) {
        char* lV = lK + 8192;
#pragma unroll
        for (int i = 0; i < 2; ++i) {
            const int chunk = i * 4 + w;
            const int row = chunk * 8 + srow;
            gload16(Kbase + (size_t)(kv0 + row) * 2048 + scol, lK + chunk * 1024);
            gload16(Vbase + (size_t)row * 4096 + (size_t)kv0 * 2 + scol, lV + chunk * 1024);
        }
    };

    const __bf16* qrow = Qb + (sbase + q0w + l31) * 1024 + hoff + 8 * hi;
    bf16x8 qf[4];
#pragma unroll
    for (int cq = 0; cq < 4; ++cq) qf[cq] = *(const bf16x8*)(qrow + 16 * cq);

    f32x16 o0 = {}, o1 = {};
    float mrun = -__builtin_inff(), lrun = 0.f;

    stage(0, lds);

    for (int tt = 0; tt < nt; ++tt) {
        const int cur = tt & 1;
        char* lcur = lds + cur * 16384;
        __builtin_amdgcn_s_barrier();  // all waves done reading buf[cur^1]
        if (tt + 1 < nt) {
            stage((tt + 1) * 64, lds + (cur ^ 1) * 16384);
            WAITVM4;   // tile tt's 4 ops (per wave) complete; tt+1 in flight
        } else {
            WAITVM0;
        }
        __builtin_amdgcn_s_barrier();  // tile tt fully staged (all waves)
        __builtin_amdgcn_sched_barrier(0);

        const int kv0 = tt * 64;
        const char* lK = lcur;
        const char* lV = lcur + 8192;

        // QK^T (swapped): S^T[kv][q]
        f32x16 s0 = {}, s1 = {};
        __builtin_amdgcn_s_setprio(1);
#pragma unroll
        for (int cc = 0; cc < 4; ++cc) {
            bf16x8 k0 = *(const bf16x8*)(lK + l31 * 128 + colx[cc]);
            bf16x8 k1 = *(const bf16x8*)(lK + (l31 + 32) * 128 + colx[cc]);
            s0 = __builtin_amdgcn_mfma_f32_32x32x16_bf16(k0, qf[cc], s0, 0, 0, 0);
            s1 = __builtin_amdgcn_mfma_f32_32x32x16_bf16(k1, qf[cc], s1, 0, 0, 0);
        }
        __builtin_amdgcn_s_setprio(0);

        float pp[32];
#pragma unroll
        for (int rr = 0; rr < 16; ++rr) { pp[rr] = s0[rr]; pp[16 + rr] = s1[rr]; }
        if (kv0 + 63 > q0w) {  // diagonal or fully-masked tile: causal mask
#pragma unroll
            for (int rr = 0; rr < 16; ++rr) {
                const int kvl = (rr & 3) + 8 * (rr >> 2) + 4 * hi;
                if (kv0 + kvl > q)      pp[rr]      = -__builtin_inff();
                if (kv0 + 32 + kvl > q) pp[16 + rr] = -__builtin_inff();
            }
        }
        float m8[8];
#pragma unroll
        for (int i = 0; i < 8; ++i)
            m8[i] = fmaxf(fmaxf(pp[4 * i], pp[4 * i + 1]), fmaxf(pp[4 * i + 2], pp[4 * i + 3]));
        float tmax = fmaxf(fmaxf(fmaxf(m8[0], m8[1]), fmaxf(m8[2], m8[3])),
                           fmaxf(fmaxf(m8[4], m8[5]), fmaxf(m8[6], m8[7])));
        const bool skip = __all(tmax <= mrun + 8.f);  // defer-max (T13)
        if (!skip) {
            float tq = fmaxf(tmax, __shfl_xor(tmax, 32));
            float mnew = fmaxf(mrun, tq);
            float al = __builtin_amdgcn_exp2f(mrun - mnew);
            lrun *= al;
#pragma unroll
            for (int rr = 0; rr < 16; ++rr) { o0[rr] *= al; o1[rr] *= al; }
            mrun = mnew;
        }
#pragma unroll
        for (int rr = 0; rr < 32; ++rr) pp[rr] = __builtin_amdgcn_exp2f(pp[rr] - mrun);
        float s8[8];
#pragma unroll
        for (int i = 0; i < 8; ++i)
            s8[i] = (pp[4 * i] + pp[4 * i + 1]) + (pp[4 * i + 2] + pp[4 * i + 3]);
        float rsum = ((s8[0] + s8[1]) + (s8[2] + s8[3])) + ((s8[4] + s8[5]) + (s8[6] + s8[7]));
        rsum += __shfl_xor(rsum, 32);
        lrun += rsum;

        // P -> B-frags: permlane32_swap(A,B): A.hi<->B.lo => words kv 8hi+0..3 / 8hi+8..11
        __builtin_amdgcn_s_setprio(1);
#pragma unroll
        for (int cc = 0; cc < 4; ++cc) {
            const int pb = cc * 8;
            unsigned int A0 = cvtpk_bf16(pp[pb + 0], pp[pb + 1]);
            unsigned int A1 = cvtpk_bf16(pp[pb + 2], pp[pb + 3]);
            unsigned int B0 = cvtpk_bf16(pp[pb + 4], pp[pb + 5]);
            unsigned int B1 = cvtpk_bf16(pp[pb + 6], pp[pb + 7]);
            asm("v_permlane32_swap_b32 %0, %1" : "+v"(A0), "+v"(B0));
            asm("v_permlane32_swap_b32 %0, %1" : "+v"(A1), "+v"(B1));
            u32x4_t wvv; wvv[0] = A0; wvv[1] = A1; wvv[2] = B0; wvv[3] = B1;
            bf16x8 pa = __builtin_bit_cast(bf16x8, wvv);
            const int vcol = (32 * cc + 16 * hi) ^ sw;
            bf16x8 v0 = *(const bf16x8*)(lV + l31 * 128 + vcol);
            bf16x8 v1 = *(const bf16x8*)(lV + (l31 + 32) * 128 + vcol);
            o0 = __builtin_amdgcn_mfma_f32_32x32x16_bf16(v0, pa, o0, 0, 0, 0);
            o1 = __builtin_amdgcn_mfma_f32_32x32x16_bf16(v1, pa, o1, 0, 0, 0);
        }
        __builtin_amdgcn_s_setprio(0);
    }

    const float inv = 1.f / lrun;
    __bf16* orow = Ob + (sbase + q0w + l31) * 1024 + hoff;
#pragma unroll
    for (int rq = 0; rq < 4; ++rq) {
        bf16x4 e0, e1;
#pragma unroll
        for (int jj = 0; jj < 4; ++jj) {
            e0[jj] = (__bf16)(o0[rq * 4 + jj] * inv);
            e1[jj] = (__bf16)(o1[rq * 4 + jj] * inv);
        }
        *(bf16x4*)(orow + 4 * hi + 8 * rq) = e0;
        *(bf16x4*)(orow + 32 + 4 * hi + 8 * rq) = e1;
    }
}

// ---------------------------------------------------------------- launch
extern "C" void kernel_launch(void* const* d_in, const int* in_sizes, int n_in,
                              void* d_out, int out_size, void* d_ws, size_t ws_size,
                              hipStream_t stream) {
    const float* x  = (const float*)d_in[0];
    const float* wq = (const float*)d_in[1];
    const float* wk = (const float*)d_in[2];
    const float* wv = (const float*)d_in[3];
    const float* wo = (const float*)d_in[4];

    char* ws = (char*)d_ws;
    __bf16* xb = (__bf16*)(ws);
    __bf16* wb = (__bf16*)(ws + 16777216);
    __bf16* Qb = (__bf16*)(ws + 25165824);
    __bf16* Kb = (__bf16*)(ws + 41943040);
    __bf16* Vt = (__bf16*)(ws + 58720256);   // [b][h][d][s]
    __bf16* Ob = (__bf16*)(ws + 75497472);

    const float qscale = 0.18033688011112043f;  // (1/sqrt(64)) * log2(e)

    cast_kernel<<<6144, 256, 0, stream>>>(x, wq, wk, wv, wo, xb, wb);
    gemm_qkv_kernel<<<768, 512, 0, stream>>>(xb, wb, Qb, Kb, Vt, qscale);
    attn_kernel<<<1024, 256, 0, stream>>>(Qb, Kb, Vt, Ob);
    gemm_out_kernel<<<256, 512, 0, stream>>>(Ob, wb + 3145728, (float*)d_out);
}

// Round 3
// 203.269 us; speedup vs baseline: 1.0083x; 1.0083x over previous
//
#include <hip/hip_runtime.h>
#include <hip/hip_bf16.h>

// B=4, S=2048, D=1024, H=16, dk=64. M = B*S = 8192.
// All GEMMs: C[m,n] = sum_k A[m,k] * W[n,k]  (W row-major [out][in], "NT")

typedef __bf16 bf16x8 __attribute__((ext_vector_type(8)));
typedef __bf16 bf16x4 __attribute__((ext_vector_type(4)));
typedef float  f32x4  __attribute__((ext_vector_type(4)));
typedef float  f32x16 __attribute__((ext_vector_type(16)));
typedef unsigned int u32x4_t __attribute__((ext_vector_type(4)));

#define GLOBAL_AS __attribute__((address_space(1)))
#define LDS_AS    __attribute__((address_space(3)))

__device__ __forceinline__ void gload16(const void* g, void* l) {
    __builtin_amdgcn_global_load_lds((const GLOBAL_AS void*)g, (LDS_AS void*)l, 16, 0, 0);
}

__device__ __forceinline__ unsigned int cvtpk_bf16(float lo, float hi) {
    unsigned int r;
    asm("v_cvt_pk_bf16_f32 %0, %1, %2" : "=v"(r) : "v"(lo), "v"(hi));
    return r;
}

#define WAITVM6 asm volatile("s_waitcnt vmcnt(6)" ::: "memory")
#define WAITVM4 asm volatile("s_waitcnt vmcnt(4)" ::: "memory")
#define WAITVM0 asm volatile("s_waitcnt vmcnt(0)" ::: "memory")
#define SCHEDB  __builtin_amdgcn_sched_barrier(0)

// ---------------------------------------------------------------- cast kernel
__global__ __launch_bounds__(256) void cast_kernel(
    const float* __restrict__ x, const float* __restrict__ wq,
    const float* __restrict__ wk, const float* __restrict__ wv,
    const float* __restrict__ wo, __bf16* __restrict__ xb, __bf16* __restrict__ wb) {
    int bid = blockIdx.x;
    const float* src; __bf16* dst; int base;
    if (bid < 4096) {
        src = x; dst = xb; base = bid * 2048;
    } else {
        int r = bid - 4096; int wi = r >> 9;
        src = (wi == 0) ? wq : (wi == 1) ? wk : (wi == 2) ? wv : wo;
        dst = wb + wi * 1048576; base = (r & 511) * 2048;
    }
    int idx = base + threadIdx.x * 8;
    float4 a = *(const float4*)(src + idx);
    float4 b = *(const float4*)(src + idx + 4);
    bf16x8 o;
    o[0] = (__bf16)a.x; o[1] = (__bf16)a.y; o[2] = (__bf16)a.z; o[3] = (__bf16)a.w;
    o[4] = (__bf16)b.x; o[5] = (__bf16)b.y; o[6] = (__bf16)b.z; o[7] = (__bf16)b.w;
    *(bf16x8*)(dst + idx) = o;
}

// ---------------------------------------------------------------- fused QKV GEMM
// 128(M) x 256(N) tile, BK=64, 512 thr / 8 waves (2Mx4N), wave tile 64x64.
// Triple-buffered LDS (3 x 48KB), counted vmcnt(6) pipeline (T3+T4), XOR-swizzled
// LDS rows via pre-swizzled global_load_lds source (T2, both-sides), setprio (T5).
// Grid 768 = 64 mt x 12 nt, XCD-swizzled (768 % 8 == 0 -> bijective).
// nt 0-3 -> Qb (scaled, swapped-mfma epi); 4-7 -> Kb; 8-11 -> Vt[b][h][d][s].
__global__ __launch_bounds__(512, 2) void gemm_qkv_kernel(
    const __bf16* __restrict__ A, const __bf16* __restrict__ W,
    __bf16* __restrict__ Qb, __bf16* __restrict__ Kb, __bf16* __restrict__ Vt,
    float qscale) {
    __shared__ __align__(16) char lds[147456];  // 3 x (A 16KB + B 32KB)
    const int t = threadIdx.x;
    const int wid = t >> 6, lane = t & 63;
    const int g = lane >> 4, m = lane & 15;
    const int wm = wid >> 2, wn = wid & 3;
    const int bid = (blockIdx.x & 7) * 96 + (blockIdx.x >> 3);
    const int mt = bid / 12, nt = bid % 12;
    const int m0 = mt * 128, n0 = nt * 256;
    const bool isV = (n0 >= 2048);

    // --- staging: per-thread pre-swizzled global sources, linear LDS dest ---
    const __bf16* sA[2]; int dA[2];
#pragma unroll
    for (int i = 0; i < 2; ++i) {
        const int ci = i * 512 + t;
        const int row = ci >> 3;
        const int k8 = (ci & 7) ^ (row & 7);
        sA[i] = A + (size_t)(m0 + row) * 1024 + k8 * 8;
        dA[i] = ci * 16;
    }
    const __bf16* sB[4]; int dB[4];
#pragma unroll
    for (int i = 0; i < 4; ++i) {
        const int ci = i * 512 + t;
        const int row = ci >> 3;
        const int k8 = (ci & 7) ^ (row & 7);
        sB[i] = W + (size_t)(n0 + row) * 1024 + k8 * 8;
        dB[i] = ci * 16;
    }
    auto stage = [&](int kt, char* buf) {
        gload16(sA[0] + kt * 64, buf + dA[0]);
        gload16(sA[1] + kt * 64, buf + dA[1]);
        gload16(sB[0] + kt * 64, buf + 16384 + dB[0]);
        gload16(sB[1] + kt * 64, buf + 16384 + dB[1]);
        gload16(sB[2] + kt * 64, buf + 16384 + dB[2]);
        gload16(sB[3] + kt * 64, buf + 16384 + dB[3]);
    };

    // --- fragment read offsets (swizzle = ((row&7)<<4), row&7 == m&7) ---
    const int sw = (m & 7) << 4;
    const int offA = (wm * 64 + m) * 128 + ((g << 4) ^ sw);
    const int offB = (wn * 64 + m) * 128 + ((g << 4) ^ sw);

    // --- prologue: tiles 0,1 in flight; wait tile0 only ---
    stage(0, lds);
    stage(1, lds + 49152);
    WAITVM6;
    SCHEDB;
    __builtin_amdgcn_s_barrier();
    SCHEDB;

    f32x4 acc[4][4] = {};
    for (int kt = 0; kt < 16; ++kt) {
        char* cbuf = lds + (kt % 3) * 49152;
        if (kt < 14) stage(kt + 2, lds + ((kt + 2) % 3) * 49152);
        const char* bA = cbuf;
        const char* bB = cbuf + 16384;
        bf16x8 a0[4], b0[4], a1[4], b1[4];
#pragma unroll
        for (int i = 0; i < 4; ++i) {
            a0[i] = *(const bf16x8*)(bA + (offA + i * 2048));
            b0[i] = *(const bf16x8*)(bB + (offB + i * 2048));
            a1[i] = *(const bf16x8*)(bA + ((offA + i * 2048) ^ 64));
            b1[i] = *(const bf16x8*)(bB + ((offB + i * 2048) ^ 64));
        }
        __builtin_amdgcn_s_setprio(1);
        if (isV) {
#pragma unroll
            for (int mi = 0; mi < 4; ++mi)
#pragma unroll
                for (int ni = 0; ni < 4; ++ni)
                    acc[mi][ni] = __builtin_amdgcn_mfma_f32_16x16x32_bf16(a0[mi], b0[ni], acc[mi][ni], 0, 0, 0);
#pragma unroll
            for (int mi = 0; mi < 4; ++mi)
#pragma unroll
                for (int ni = 0; ni < 4; ++ni)
                    acc[mi][ni] = __builtin_amdgcn_mfma_f32_16x16x32_bf16(a1[mi], b1[ni], acc[mi][ni], 0, 0, 0);
        } else {
#pragma unroll
            for (int mi = 0; mi < 4; ++mi)
#pragma unroll
                for (int ni = 0; ni < 4; ++ni)
                    acc[mi][ni] = __builtin_amdgcn_mfma_f32_16x16x32_bf16(b0[ni], a0[mi], acc[mi][ni], 0, 0, 0);
#pragma unroll
            for (int mi = 0; mi < 4; ++mi)
#pragma unroll
                for (int ni = 0; ni < 4; ++ni)
                    acc[mi][ni] = __builtin_amdgcn_mfma_f32_16x16x32_bf16(b1[ni], a1[mi], acc[mi][ni], 0, 0, 0);
        }
        __builtin_amdgcn_s_setprio(0);
        if (kt < 14) { WAITVM6; }          // tile kt+1 staged; kt+2's 6 ops in flight
        else if (kt == 14) { WAITVM0; }    // tail: tile 15 staged
        if (kt < 15) {
            SCHEDB;
            __builtin_amdgcn_s_barrier();
            SCHEDB;
        }
    }

    if (isV) {
        const int bb = m0 >> 11;
        const int sb = (m0 & 2047) + wm * 64 + 4 * g;
        const int hbase = ((n0 - 2048) >> 6) + wn;
#pragma unroll
        for (int mi = 0; mi < 4; ++mi)
#pragma unroll
            for (int ni = 0; ni < 4; ++ni) {
                const int d = ni * 16 + m;
                bf16x4 pk;
                pk[0] = (__bf16)(acc[mi][ni][0]); pk[1] = (__bf16)(acc[mi][ni][1]);
                pk[2] = (__bf16)(acc[mi][ni][2]); pk[3] = (__bf16)(acc[mi][ni][3]);
                *(bf16x4*)(Vt + ((size_t)(bb * 16 + hbase) * 64 + d) * 2048 + sb + mi * 16) = pk;
            }
    } else {
        __bf16* C = (n0 < 1024) ? Qb : Kb;
        const float sc = (n0 < 1024) ? qscale : 1.f;
        const int cb = (n0 & 1023) + wn * 64 + 4 * g;
        const int row = m0 + wm * 64 + m;
#pragma unroll
        for (int mi = 0; mi < 4; ++mi)
#pragma unroll
            for (int ni = 0; ni < 4; ++ni) {
                bf16x4 pk;
                pk[0] = (__bf16)(acc[mi][ni][0] * sc); pk[1] = (__bf16)(acc[mi][ni][1] * sc);
                pk[2] = (__bf16)(acc[mi][ni][2] * sc); pk[3] = (__bf16)(acc[mi][ni][3] * sc);
                *(bf16x4*)(C + (size_t)(row + mi * 16) * 1024 + cb + ni * 16) = pk;
            }
    }
}

// ---------------------------------------------------------------- output GEMM (f32)
__global__ __launch_bounds__(512, 2) void gemm_out_kernel(
    const __bf16* __restrict__ A, const __bf16* __restrict__ W, float* __restrict__ out) {
    __shared__ __align__(16) char lds[147456];
    const int t = threadIdx.x;
    const int wid = t >> 6, lane = t & 63;
    const int g = lane >> 4, m = lane & 15;
    const int wm = wid >> 2, wn = wid & 3;
    const int bid = (blockIdx.x & 7) * 32 + (blockIdx.x >> 3);
    const int mt = bid >> 2, nt = bid & 3;
    const int m0 = mt * 128, n0 = nt * 256;

    const __bf16* sA[2]; int dA[2];
#pragma unroll
    for (int i = 0; i < 2; ++i) {
        const int ci = i * 512 + t;
        const int row = ci >> 3;
        const int k8 = (ci & 7) ^ (row & 7);
        sA[i] = A + (size_t)(m0 + row) * 1024 + k8 * 8;
        dA[i] = ci * 16;
    }
    const __bf16* sB[4]; int dB[4];
#pragma unroll
    for (int i = 0; i < 4; ++i) {
        const int ci = i * 512 + t;
        const int row = ci >> 3;
        const int k8 = (ci & 7) ^ (row & 7);
        sB[i] = W + (size_t)(n0 + row) * 1024 + k8 * 8;
        dB[i] = ci * 16;
    }
    auto stage = [&](int kt, char* buf) {
        gload16(sA[0] + kt * 64, buf + dA[0]);
        gload16(sA[1] + kt * 64, buf + dA[1]);
        gload16(sB[0] + kt * 64, buf + 16384 + dB[0]);
        gload16(sB[1] + kt * 64, buf + 16384 + dB[1]);
        gload16(sB[2] + kt * 64, buf + 16384 + dB[2]);
        gload16(sB[3] + kt * 64, buf + 16384 + dB[3]);
    };

    const int sw = (m & 7) << 4;
    const int offA = (wm * 64 + m) * 128 + ((g << 4) ^ sw);
    const int offB = (wn * 64 + m) * 128 + ((g << 4) ^ sw);

    stage(0, lds);
    stage(1, lds + 49152);
    WAITVM6;
    SCHEDB;
    __builtin_amdgcn_s_barrier();
    SCHEDB;

    f32x4 acc[4][4] = {};
    for (int kt = 0; kt < 16; ++kt) {
        char* cbuf = lds + (kt % 3) * 49152;
        if (kt < 14) stage(kt + 2, lds + ((kt + 2) % 3) * 49152);
        const char* bA = cbuf;
        const char* bB = cbuf + 16384;
        bf16x8 a0[4], b0[4], a1[4], b1[4];
#pragma unroll
        for (int i = 0; i < 4; ++i) {
            a0[i] = *(const bf16x8*)(bA + (offA + i * 2048));
            b0[i] = *(const bf16x8*)(bB + (offB + i * 2048));
            a1[i] = *(const bf16x8*)(bA + ((offA + i * 2048) ^ 64));
            b1[i] = *(const bf16x8*)(bB + ((offB + i * 2048) ^ 64));
        }
        __builtin_amdgcn_s_setprio(1);
#pragma unroll
        for (int mi = 0; mi < 4; ++mi)
#pragma unroll
            for (int ni = 0; ni < 4; ++ni)
                acc[mi][ni] = __builtin_amdgcn_mfma_f32_16x16x32_bf16(b0[ni], a0[mi], acc[mi][ni], 0, 0, 0);
#pragma unroll
        for (int mi = 0; mi < 4; ++mi)
#pragma unroll
            for (int ni = 0; ni < 4; ++ni)
                acc[mi][ni] = __builtin_amdgcn_mfma_f32_16x16x32_bf16(b1[ni], a1[mi], acc[mi][ni], 0, 0, 0);
        __builtin_amdgcn_s_setprio(0);
        if (kt < 14) { WAITVM6; }
        else if (kt == 14) { WAITVM0; }
        if (kt < 15) {
            SCHEDB;
            __builtin_amdgcn_s_barrier();
            SCHEDB;
        }
    }

    const int row = m0 + wm * 64 + m;
    const int col = n0 + wn * 64 + 4 * g;
#pragma unroll
    for (int mi = 0; mi < 4; ++mi)
#pragma unroll
        for (int ni = 0; ni < 4; ++ni)
            *(f32x4*)(out + (size_t)(row + mi * 16) * 1024 + col + ni * 16) = acc[mi][ni];
}

// ---------------------------------------------------------------- flash attention v7
// = v6 structure (4 waves / 256 thr share one K/V LDS double-buffer; block owns a
// 128-row Q panel; strip-paired XCD-local index map) with the round-2 bug fixed:
// NO forced min-waves in __launch_bounds__. Round 2's (256,4) capped arch VGPRs
// at 64 -> scratch spills (+19MB WRITE, +10MB FETCH, dur 80->99us). Natural
// allocation (~124 regs, proven in round 1) still permits ~4 waves/SIMD.
__global__ __launch_bounds__(256) void attn_kernel(
    const __bf16* __restrict__ Qb, const __bf16* __restrict__ Kb,
    const __bf16* __restrict__ Vt, __bf16* __restrict__ Ob) {
    __shared__ __align__(16) char lds[32768];  // 2 bufs x (K 8KB + V 8KB)
    const int t = threadIdx.x;
    const int w = t >> 6, lane = t & 63;
    const int l31 = lane & 31, hi = lane >> 5;
    // launch idx x: xcd = x&7; p = x>>3; r = p>>5 (residency round), c = p&31;
    // strip = (r&1) ? 15-(c&15) : (c&15); bh_local = (c>>4) + 2r; bh = xcd | bh_local<<3
    const int x = blockIdx.x;
    const int p = x >> 3;
    const int r = p >> 5, c = p & 31, j = c & 15;
    const int strip = (r & 1) ? (15 - j) : j;
    const int bh = (x & 7) | (((c >> 4) + 2 * r) << 3);
    const size_t sbase = (size_t)(bh >> 4) * 2048;
    const int hoff = (bh & 15) * 64;

    const int q0w = strip * 128 + w * 32;
    const int nt = 2 * (strip + 1);
    const int q = q0w + l31;

    const char* Kbase = (const char*)Kb + (sbase * 1024 + hoff) * 2;
    const char* Vbase = (const char*)Vt + (size_t)bh * 262144;
    const int srow = lane >> 3;
    const int scol = ((lane & 7) ^ srow) << 4;  // pre-swizzled source slot
    const int sw = (l31 & 7) << 4;              // read-side swizzle
    int colx[4];
#pragma unroll
    for (int i = 0; i < 4; ++i) colx[i] = (32 * i + 16 * hi) ^ sw;

    // stage one K+V tile (16 chunks of 1KB) split across 4 waves: 4 gload16/wave
    auto stage = [&](int kv0, char* lK) {
        char* lV = lK + 8192;
#pragma unroll
        for (int i = 0; i < 2; ++i) {
            const int chunk = i * 4 + w;
            const int row = chunk * 8 + srow;
            gload16(Kbase + (size_t)(kv0 + row) * 2048 + scol, lK + chunk * 1024);
            gload16(Vbase + (size_t)row * 4096 + (size_t)kv0 * 2 + scol, lV + chunk * 1024);
        }
    };

    const __bf16* qrow = Qb + (sbase + q0w + l31) * 1024 + hoff + 8 * hi;
    bf16x8 qf[4];
#pragma unroll
    for (int cq = 0; cq < 4; ++cq) qf[cq] = *(const bf16x8*)(qrow + 16 * cq);

    f32x16 o0 = {}, o1 = {};
    float mrun = -__builtin_inff(), lrun = 0.f;

    stage(0, lds);

    for (int tt = 0; tt < nt; ++tt) {
        const int cur = tt & 1;
        char* lcur = lds + cur * 16384;
        __builtin_amdgcn_s_barrier();  // all waves done reading buf[cur^1]
        if (tt + 1 < nt) {
            stage((tt + 1) * 64, lds + (cur ^ 1) * 16384);
            WAITVM4;   // tile tt's 4 ops (per wave) complete; tt+1 in flight
        } else {
            WAITVM0;
        }
        __builtin_amdgcn_s_barrier();  // tile tt fully staged (all waves)
        __builtin_amdgcn_sched_barrier(0);

        const int kv0 = tt * 64;
        const char* lK = lcur;
        const char* lV = lcur + 8192;

        // QK^T (swapped): S^T[kv][q]
        f32x16 s0 = {}, s1 = {};
        __builtin_amdgcn_s_setprio(1);
#pragma unroll
        for (int cc = 0; cc < 4; ++cc) {
            bf16x8 k0 = *(const bf16x8*)(lK + l31 * 128 + colx[cc]);
            bf16x8 k1 = *(const bf16x8*)(lK + (l31 + 32) * 128 + colx[cc]);
            s0 = __builtin_amdgcn_mfma_f32_32x32x16_bf16(k0, qf[cc], s0, 0, 0, 0);
            s1 = __builtin_amdgcn_mfma_f32_32x32x16_bf16(k1, qf[cc], s1, 0, 0, 0);
        }
        __builtin_amdgcn_s_setprio(0);

        float pp[32];
#pragma unroll
        for (int rr = 0; rr < 16; ++rr) { pp[rr] = s0[rr]; pp[16 + rr] = s1[rr]; }
        if (kv0 + 63 > q0w) {  // diagonal or fully-masked tile: causal mask
#pragma unroll
            for (int rr = 0; rr < 16; ++rr) {
                const int kvl = (rr & 3) + 8 * (rr >> 2) + 4 * hi;
                if (kv0 + kvl > q)      pp[rr]      = -__builtin_inff();
                if (kv0 + 32 + kvl > q) pp[16 + rr] = -__builtin_inff();
            }
        }
        float m8[8];
#pragma unroll
        for (int i = 0; i < 8; ++i)
            m8[i] = fmaxf(fmaxf(pp[4 * i], pp[4 * i + 1]), fmaxf(pp[4 * i + 2], pp[4 * i + 3]));
        float tmax = fmaxf(fmaxf(fmaxf(m8[0], m8[1]), fmaxf(m8[2], m8[3])),
                           fmaxf(fmaxf(m8[4], m8[5]), fmaxf(m8[6], m8[7])));
        const bool skip = __all(tmax <= mrun + 8.f);  // defer-max (T13)
        if (!skip) {
            float tq = fmaxf(tmax, __shfl_xor(tmax, 32));
            float mnew = fmaxf(mrun, tq);
            float al = __builtin_amdgcn_exp2f(mrun - mnew);
            lrun *= al;
#pragma unroll
            for (int rr = 0; rr < 16; ++rr) { o0[rr] *= al; o1[rr] *= al; }
            mrun = mnew;
        }
#pragma unroll
        for (int rr = 0; rr < 32; ++rr) pp[rr] = __builtin_amdgcn_exp2f(pp[rr] - mrun);
        float s8[8];
#pragma unroll
        for (int i = 0; i < 8; ++i)
            s8[i] = (pp[4 * i] + pp[4 * i + 1]) + (pp[4 * i + 2] + pp[4 * i + 3]);
        float rsum = ((s8[0] + s8[1]) + (s8[2] + s8[3])) + ((s8[4] + s8[5]) + (s8[6] + s8[7]));
        rsum += __shfl_xor(rsum, 32);
        lrun += rsum;

        // P -> B-frags: permlane32_swap(A,B): A.hi<->B.lo => words kv 8hi+0..3 / 8hi+8..11
        __builtin_amdgcn_s_setprio(1);
#pragma unroll
        for (int cc = 0; cc < 4; ++cc) {
            const int pb = cc * 8;
            unsigned int A0 = cvtpk_bf16(pp[pb + 0], pp[pb + 1]);
            unsigned int A1 = cvtpk_bf16(pp[pb + 2], pp[pb + 3]);
            unsigned int B0 = cvtpk_bf16(pp[pb + 4], pp[pb + 5]);
            unsigned int B1 = cvtpk_bf16(pp[pb + 6], pp[pb + 7]);
            asm("v_permlane32_swap_b32 %0, %1" : "+v"(A0), "+v"(B0));
            asm("v_permlane32_swap_b32 %0, %1" : "+v"(A1), "+v"(B1));
            u32x4_t wvv; wvv[0] = A0; wvv[1] = A1; wvv[2] = B0; wvv[3] = B1;
            bf16x8 pa = __builtin_bit_cast(bf16x8, wvv);
            const int vcol = (32 * cc + 16 * hi) ^ sw;
            bf16x8 v0 = *(const bf16x8*)(lV + l31 * 128 + vcol);
            bf16x8 v1 = *(const bf16x8*)(lV + (l31 + 32) * 128 + vcol);
            o0 = __builtin_amdgcn_mfma_f32_32x32x16_bf16(v0, pa, o0, 0, 0, 0);
            o1 = __builtin_amdgcn_mfma_f32_32x32x16_bf16(v1, pa, o1, 0, 0, 0);
        }
        __builtin_amdgcn_s_setprio(0);
    }

    const float inv = 1.f / lrun;
    __bf16* orow = Ob + (sbase + q0w + l31) * 1024 + hoff;
#pragma unroll
    for (int rq = 0; rq < 4; ++rq) {
        bf16x4 e0, e1;
#pragma unroll
        for (int jj = 0; jj < 4; ++jj) {
            e0[jj] = (__bf16)(o0[rq * 4 + jj] * inv);
            e1[jj] = (__bf16)(o1[rq * 4 + jj] * inv);
        }
        *(bf16x4*)(orow + 4 * hi + 8 * rq) = e0;
        *(bf16x4*)(orow + 32 + 4 * hi + 8 * rq) = e1;
    }
}

// ---------------------------------------------------------------- launch
extern "C" void kernel_launch(void* const* d_in, const int* in_sizes, int n_in,
                              void* d_out, int out_size, void* d_ws, size_t ws_size,
                              hipStream_t stream) {
    const float* x  = (const float*)d_in[0];
    const float* wq = (const float*)d_in[1];
    const float* wk = (const float*)d_in[2];
    const float* wv = (const float*)d_in[3];
    const float* wo = (const float*)d_in[4];

    char* ws = (char*)d_ws;
    __bf16* xb = (__bf16*)(ws);
    __bf16* wb = (__bf16*)(ws + 16777216);
    __bf16* Qb = (__bf16*)(ws + 25165824);
    __bf16* Kb = (__bf16*)(ws + 41943040);
    __bf16* Vt = (__bf16*)(ws + 58720256);   // [b][h][d][s]
    __bf16* Ob = (__bf16*)(ws + 75497472);

    const float qscale = 0.18033688011112043f;  // (1/sqrt(64)) * log2(e)

    cast_kernel<<<6144, 256, 0, stream>>>(x, wq, wk, wv, wo, xb, wb);
    gemm_qkv_kernel<<<768, 512, 0, stream>>>(xb, wb, Qb, Kb, Vt, qscale);
    attn_kernel<<<1024, 256, 0, stream>>>(Qb, Kb, Vt, Ob);
    gemm_out_kernel<<<256, 512, 0, stream>>>(Ob, wb + 3145728, (float*)d_out);
}

// Round 4
// 180.915 us; speedup vs baseline: 1.1329x; 1.1236x over previous
//
#include <hip/hip_runtime.h>
#include <hip/hip_bf16.h>

// B=4, S=2048, D=1024, H=16, dk=64. M = B*S = 8192.
// All GEMMs: C[m,n] = sum_k A[m,k] * W[n,k]  (W row-major [out][in], "NT")

typedef __bf16 bf16x8 __attribute__((ext_vector_type(8)));
typedef __bf16 bf16x4 __attribute__((ext_vector_type(4)));
typedef float  f32x4  __attribute__((ext_vector_type(4)));
typedef float  f32x16 __attribute__((ext_vector_type(16)));
typedef unsigned int u32x4_t __attribute__((ext_vector_type(4)));

#define GLOBAL_AS __attribute__((address_space(1)))
#define LDS_AS    __attribute__((address_space(3)))

__device__ __forceinline__ void gload16(const void* g, void* l) {
    __builtin_amdgcn_global_load_lds((const GLOBAL_AS void*)g, (LDS_AS void*)l, 16, 0, 0);
}

__device__ __forceinline__ unsigned int cvtpk_bf16(float lo, float hi) {
    unsigned int r;
    asm("v_cvt_pk_bf16_f32 %0, %1, %2" : "=v"(r) : "v"(lo), "v"(hi));
    return r;
}

#define WAITVM8 asm volatile("s_waitcnt vmcnt(8)" ::: "memory")
#define WAITVM6 asm volatile("s_waitcnt vmcnt(6)" ::: "memory")
#define WAITVM0 asm volatile("s_waitcnt vmcnt(0)" ::: "memory")
#define SCHEDB  __builtin_amdgcn_sched_barrier(0)

// ---------------------------------------------------------------- cast kernel
__global__ __launch_bounds__(256) void cast_kernel(
    const float* __restrict__ x, const float* __restrict__ wq,
    const float* __restrict__ wk, const float* __restrict__ wv,
    const float* __restrict__ wo, __bf16* __restrict__ xb, __bf16* __restrict__ wb) {
    int bid = blockIdx.x;
    const float* src; __bf16* dst; int base;
    if (bid < 4096) {
        src = x; dst = xb; base = bid * 2048;
    } else {
        int r = bid - 4096; int wi = r >> 9;
        src = (wi == 0) ? wq : (wi == 1) ? wk : (wi == 2) ? wv : wo;
        dst = wb + wi * 1048576; base = (r & 511) * 2048;
    }
    int idx = base + threadIdx.x * 8;
    float4 a = *(const float4*)(src + idx);
    float4 b = *(const float4*)(src + idx + 4);
    bf16x8 o;
    o[0] = (__bf16)a.x; o[1] = (__bf16)a.y; o[2] = (__bf16)a.z; o[3] = (__bf16)a.w;
    o[4] = (__bf16)b.x; o[5] = (__bf16)b.y; o[6] = (__bf16)b.z; o[7] = (__bf16)b.w;
    *(bf16x8*)(dst + idx) = o;
}

// ---------------------------------------------------------------- fused QKV GEMM
// 128(M) x 256(N) tile, BK=64, 512 thr / 8 waves (2Mx4N), wave tile 64x64.
// Triple-buffered LDS (3 x 48KB), counted vmcnt(6) pipeline (T3+T4), XOR-swizzled
// LDS rows via pre-swizzled global_load_lds source (T2, both-sides), setprio (T5).
// Grid 768 = 64 mt x 12 nt, XCD-swizzled (768 % 8 == 0 -> bijective).
// nt 0-3 -> Qb (scaled, swapped-mfma epi); 4-7 -> Kb; 8-11 -> Vt[b][h][d][s].
__global__ __launch_bounds__(512, 2) void gemm_qkv_kernel(
    const __bf16* __restrict__ A, const __bf16* __restrict__ W,
    __bf16* __restrict__ Qb, __bf16* __restrict__ Kb, __bf16* __restrict__ Vt,
    float qscale) {
    __shared__ __align__(16) char lds[147456];  // 3 x (A 16KB + B 32KB)
    const int t = threadIdx.x;
    const int wid = t >> 6, lane = t & 63;
    const int g = lane >> 4, m = lane & 15;
    const int wm = wid >> 2, wn = wid & 3;
    const int bid = (blockIdx.x & 7) * 96 + (blockIdx.x >> 3);
    const int mt = bid / 12, nt = bid % 12;
    const int m0 = mt * 128, n0 = nt * 256;
    const bool isV = (n0 >= 2048);

    // --- staging: per-thread pre-swizzled global sources, linear LDS dest ---
    const __bf16* sA[2]; int dA[2];
#pragma unroll
    for (int i = 0; i < 2; ++i) {
        const int ci = i * 512 + t;
        const int row = ci >> 3;
        const int k8 = (ci & 7) ^ (row & 7);
        sA[i] = A + (size_t)(m0 + row) * 1024 + k8 * 8;
        dA[i] = ci * 16;
    }
    const __bf16* sB[4]; int dB[4];
#pragma unroll
    for (int i = 0; i < 4; ++i) {
        const int ci = i * 512 + t;
        const int row = ci >> 3;
        const int k8 = (ci & 7) ^ (row & 7);
        sB[i] = W + (size_t)(n0 + row) * 1024 + k8 * 8;
        dB[i] = ci * 16;
    }
    auto stage = [&](int kt, char* buf) {
        gload16(sA[0] + kt * 64, buf + dA[0]);
        gload16(sA[1] + kt * 64, buf + dA[1]);
        gload16(sB[0] + kt * 64, buf + 16384 + dB[0]);
        gload16(sB[1] + kt * 64, buf + 16384 + dB[1]);
        gload16(sB[2] + kt * 64, buf + 16384 + dB[2]);
        gload16(sB[3] + kt * 64, buf + 16384 + dB[3]);
    };

    // --- fragment read offsets (swizzle = ((row&7)<<4), row&7 == m&7) ---
    const int sw = (m & 7) << 4;
    const int offA = (wm * 64 + m) * 128 + ((g << 4) ^ sw);
    const int offB = (wn * 64 + m) * 128 + ((g << 4) ^ sw);

    // --- prologue: tiles 0,1 in flight; wait tile0 only ---
    stage(0, lds);
    stage(1, lds + 49152);
    WAITVM6;
    SCHEDB;
    __builtin_amdgcn_s_barrier();
    SCHEDB;

    f32x4 acc[4][4] = {};
    for (int kt = 0; kt < 16; ++kt) {
        char* cbuf = lds + (kt % 3) * 49152;
        if (kt < 14) stage(kt + 2, lds + ((kt + 2) % 3) * 49152);
        const char* bA = cbuf;
        const char* bB = cbuf + 16384;
        bf16x8 a0[4], b0[4], a1[4], b1[4];
#pragma unroll
        for (int i = 0; i < 4; ++i) {
            a0[i] = *(const bf16x8*)(bA + (offA + i * 2048));
            b0[i] = *(const bf16x8*)(bB + (offB + i * 2048));
            a1[i] = *(const bf16x8*)(bA + ((offA + i * 2048) ^ 64));
            b1[i] = *(const bf16x8*)(bB + ((offB + i * 2048) ^ 64));
        }
        __builtin_amdgcn_s_setprio(1);
        if (isV) {
#pragma unroll
            for (int mi = 0; mi < 4; ++mi)
#pragma unroll
                for (int ni = 0; ni < 4; ++ni)
                    acc[mi][ni] = __builtin_amdgcn_mfma_f32_16x16x32_bf16(a0[mi], b0[ni], acc[mi][ni], 0, 0, 0);
#pragma unroll
            for (int mi = 0; mi < 4; ++mi)
#pragma unroll
                for (int ni = 0; ni < 4; ++ni)
                    acc[mi][ni] = __builtin_amdgcn_mfma_f32_16x16x32_bf16(a1[mi], b1[ni], acc[mi][ni], 0, 0, 0);
        } else {
#pragma unroll
            for (int mi = 0; mi < 4; ++mi)
#pragma unroll
                for (int ni = 0; ni < 4; ++ni)
                    acc[mi][ni] = __builtin_amdgcn_mfma_f32_16x16x32_bf16(b0[ni], a0[mi], acc[mi][ni], 0, 0, 0);
#pragma unroll
            for (int mi = 0; mi < 4; ++mi)
#pragma unroll
                for (int ni = 0; ni < 4; ++ni)
                    acc[mi][ni] = __builtin_amdgcn_mfma_f32_16x16x32_bf16(b1[ni], a1[mi], acc[mi][ni], 0, 0, 0);
        }
        __builtin_amdgcn_s_setprio(0);
        if (kt < 14) { WAITVM6; }          // tile kt+1 staged; kt+2's 6 ops in flight
        else if (kt == 14) { WAITVM0; }    // tail: tile 15 staged
        if (kt < 15) {
            SCHEDB;
            __builtin_amdgcn_s_barrier();
            SCHEDB;
        }
    }

    if (isV) {
        const int bb = m0 >> 11;
        const int sb = (m0 & 2047) + wm * 64 + 4 * g;
        const int hbase = ((n0 - 2048) >> 6) + wn;
#pragma unroll
        for (int mi = 0; mi < 4; ++mi)
#pragma unroll
            for (int ni = 0; ni < 4; ++ni) {
                const int d = ni * 16 + m;
                bf16x4 pk;
                pk[0] = (__bf16)(acc[mi][ni][0]); pk[1] = (__bf16)(acc[mi][ni][1]);
                pk[2] = (__bf16)(acc[mi][ni][2]); pk[3] = (__bf16)(acc[mi][ni][3]);
                *(bf16x4*)(Vt + ((size_t)(bb * 16 + hbase) * 64 + d) * 2048 + sb + mi * 16) = pk;
            }
    } else {
        __bf16* C = (n0 < 1024) ? Qb : Kb;
        const float sc = (n0 < 1024) ? qscale : 1.f;
        const int cb = (n0 & 1023) + wn * 64 + 4 * g;
        const int row = m0 + wm * 64 + m;
#pragma unroll
        for (int mi = 0; mi < 4; ++mi)
#pragma unroll
            for (int ni = 0; ni < 4; ++ni) {
                bf16x4 pk;
                pk[0] = (__bf16)(acc[mi][ni][0] * sc); pk[1] = (__bf16)(acc[mi][ni][1] * sc);
                pk[2] = (__bf16)(acc[mi][ni][2] * sc); pk[3] = (__bf16)(acc[mi][ni][3] * sc);
                *(bf16x4*)(C + (size_t)(row + mi * 16) * 1024 + cb + ni * 16) = pk;
            }
    }
}

// ---------------------------------------------------------------- output GEMM (f32)
__global__ __launch_bounds__(512, 2) void gemm_out_kernel(
    const __bf16* __restrict__ A, const __bf16* __restrict__ W, float* __restrict__ out) {
    __shared__ __align__(16) char lds[147456];
    const int t = threadIdx.x;
    const int wid = t >> 6, lane = t & 63;
    const int g = lane >> 4, m = lane & 15;
    const int wm = wid >> 2, wn = wid & 3;
    const int bid = (blockIdx.x & 7) * 32 + (blockIdx.x >> 3);
    const int mt = bid >> 2, nt = bid & 3;
    const int m0 = mt * 128, n0 = nt * 256;

    const __bf16* sA[2]; int dA[2];
#pragma unroll
    for (int i = 0; i < 2; ++i) {
        const int ci = i * 512 + t;
        const int row = ci >> 3;
        const int k8 = (ci & 7) ^ (row & 7);
        sA[i] = A + (size_t)(m0 + row) * 1024 + k8 * 8;
        dA[i] = ci * 16;
    }
    const __bf16* sB[4]; int dB[4];
#pragma unroll
    for (int i = 0; i < 4; ++i) {
        const int ci = i * 512 + t;
        const int row = ci >> 3;
        const int k8 = (ci & 7) ^ (row & 7);
        sB[i] = W + (size_t)(n0 + row) * 1024 + k8 * 8;
        dB[i] = ci * 16;
    }
    auto stage = [&](int kt, char* buf) {
        gload16(sA[0] + kt * 64, buf + dA[0]);
        gload16(sA[1] + kt * 64, buf + dA[1]);
        gload16(sB[0] + kt * 64, buf + 16384 + dB[0]);
        gload16(sB[1] + kt * 64, buf + 16384 + dB[1]);
        gload16(sB[2] + kt * 64, buf + 16384 + dB[2]);
        gload16(sB[3] + kt * 64, buf + 16384 + dB[3]);
    };

    const int sw = (m & 7) << 4;
    const int offA = (wm * 64 + m) * 128 + ((g << 4) ^ sw);
    const int offB = (wn * 64 + m) * 128 + ((g << 4) ^ sw);

    stage(0, lds);
    stage(1, lds + 49152);
    WAITVM6;
    SCHEDB;
    __builtin_amdgcn_s_barrier();
    SCHEDB;

    f32x4 acc[4][4] = {};
    for (int kt = 0; kt < 16; ++kt) {
        char* cbuf = lds + (kt % 3) * 49152;
        if (kt < 14) stage(kt + 2, lds + ((kt + 2) % 3) * 49152);
        const char* bA = cbuf;
        const char* bB = cbuf + 16384;
        bf16x8 a0[4], b0[4], a1[4], b1[4];
#pragma unroll
        for (int i = 0; i < 4; ++i) {
            a0[i] = *(const bf16x8*)(bA + (offA + i * 2048));
            b0[i] = *(const bf16x8*)(bB + (offB + i * 2048));
            a1[i] = *(const bf16x8*)(bA + ((offA + i * 2048) ^ 64));
            b1[i] = *(const bf16x8*)(bB + ((offB + i * 2048) ^ 64));
        }
        __builtin_amdgcn_s_setprio(1);
#pragma unroll
        for (int mi = 0; mi < 4; ++mi)
#pragma unroll
            for (int ni = 0; ni < 4; ++ni)
                acc[mi][ni] = __builtin_amdgcn_mfma_f32_16x16x32_bf16(b0[ni], a0[mi], acc[mi][ni], 0, 0, 0);
#pragma unroll
        for (int mi = 0; mi < 4; ++mi)
#pragma unroll
            for (int ni = 0; ni < 4; ++ni)
                acc[mi][ni] = __builtin_amdgcn_mfma_f32_16x16x32_bf16(b1[ni], a1[mi], acc[mi][ni], 0, 0, 0);
        __builtin_amdgcn_s_setprio(0);
        if (kt < 14) { WAITVM6; }
        else if (kt == 14) { WAITVM0; }
        if (kt < 15) {
            SCHEDB;
            __builtin_amdgcn_s_barrier();
            SCHEDB;
        }
    }

    const int row = m0 + wm * 64 + m;
    const int col = n0 + wn * 64 + 4 * g;
#pragma unroll
    for (int mi = 0; mi < 4; ++mi)
#pragma unroll
        for (int ni = 0; ni < 4; ++ni)
            *(f32x4*)(out + (size_t)(row + mi * 16) * 1024 + col + ni * 16) = acc[mi][ni];
}

// ---------------------------------------------------------------- flash attention v8
// Round-1 skeleton (2 waves/block, 1024 blocks, XCD-local bh map, balanced pairing)
// with the two phases FUSED over one shared kv stream: block (bh,qb) runs strips
// A=qb and B=31-qb over tiles 0..(31-qb); A participates while tt<=qb. Work stays
// exactly 33 tile-units/block (balanced), staging drops to 32-qb tiles, and dual
// tiles give the wave two independent QK^T->softmax->PV chains to interleave
// (intra-wave ILP; grid parallelism is capped at 2 waves/SIMD). K frags read from
// LDS once, feed both strips. (128,2) caps VGPR at 256 = guaranteed 2 waves/SIMD.
__global__ __launch_bounds__(128, 2) void attn_kernel(
    const __bf16* __restrict__ Qb, const __bf16* __restrict__ Kb,
    const __bf16* __restrict__ Vt, __bf16* __restrict__ Ob) {
    __shared__ __align__(16) char lds[32768];  // 2 bufs x (K 8KB + V 8KB)
    const int t = threadIdx.x;
    const int w = t >> 6, lane = t & 63;
    const int l31 = lane & 31, hi = lane >> 5;
    // XCD remap: launch idx x -> qb = (x>>3)&15, bh = (x&7) | ((x>>7)<<3)
    const int qb = (blockIdx.x >> 3) & 15;
    const int bh = (blockIdx.x & 7) | ((blockIdx.x >> 7) << 3);
    const size_t sbase = (size_t)(bh >> 4) * 2048;
    const int hoff = (bh & 15) * 64;

    const char* Kbase = (const char*)Kb + (sbase * 1024 + hoff) * 2;
    const char* Vbase = (const char*)Vt + (size_t)bh * 262144;
    const int srow = lane >> 3;
    const int scol = ((lane & 7) ^ srow) << 4;  // pre-swizzled source slot
    const int sw = (l31 & 7) << 4;              // read-side swizzle
    int colx[4];
#pragma unroll
    for (int i = 0; i < 4; ++i) colx[i] = (32 * i + 16 * hi) ^ sw;

    // stage one K+V tile into buffer (8 gload16 per wave: 4 K-chunks + 4 V-chunks)
    auto stage = [&](int kv0, char* lK) {
        char* lV = lK + 8192;
#pragma unroll
        for (int i = 0; i < 4; ++i) {
            const int chunk = i * 2 + w;
            const int row = chunk * 8 + srow;
            gload16(Kbase + (size_t)(kv0 + row) * 2048 + scol, lK + chunk * 1024);
            gload16(Vbase + (size_t)row * 4096 + (size_t)kv0 * 2 + scol, lV + chunk * 1024);
        }
    };

    const int q0A = qb * 64 + w * 32;
    const int q0B = (31 - qb) * 64 + w * 32;
    const int qA = q0A + l31, qB = q0B + l31;
    const int nstream = 32 - qb;  // tiles 0..nstream-1 cover both strips

    const __bf16* qrowA = Qb + (sbase + q0A + l31) * 1024 + hoff + 8 * hi;
    const __bf16* qrowB = Qb + (sbase + q0B + l31) * 1024 + hoff + 8 * hi;
    bf16x8 qfA[4], qfB[4];
#pragma unroll
    for (int cq = 0; cq < 4; ++cq) {
        qfA[cq] = *(const bf16x8*)(qrowA + 16 * cq);
        qfB[cq] = *(const bf16x8*)(qrowB + 16 * cq);
    }

    f32x16 oA0 = {}, oA1 = {}, oB0 = {}, oB1 = {};
    float mA = -__builtin_inff(), lA = 0.f;
    float mB = -__builtin_inff(), lB = 0.f;

    // softmax + PV for one strip (s0r/s1r = S^T fragments; diag = causal tile)
    auto process = [&](const f32x16& s0r, const f32x16& s1r, int qq, bool diag,
                       int kv0, float& mrun, float& lrun, f32x16& o0, f32x16& o1,
                       const char* lV) {
        float pp[32];
#pragma unroll
        for (int rr = 0; rr < 16; ++rr) { pp[rr] = s0r[rr]; pp[16 + rr] = s1r[rr]; }
        if (diag) {
#pragma unroll
            for (int rr = 0; rr < 16; ++rr) {
                const int kvl = (rr & 3) + 8 * (rr >> 2) + 4 * hi;
                if (kv0 + kvl > qq)      pp[rr]      = -__builtin_inff();
                if (kv0 + 32 + kvl > qq) pp[16 + rr] = -__builtin_inff();
            }
        }
        float m8[8];
#pragma unroll
        for (int i = 0; i < 8; ++i)
            m8[i] = fmaxf(fmaxf(pp[4 * i], pp[4 * i + 1]), fmaxf(pp[4 * i + 2], pp[4 * i + 3]));
        float tmax = fmaxf(fmaxf(fmaxf(m8[0], m8[1]), fmaxf(m8[2], m8[3])),
                           fmaxf(fmaxf(m8[4], m8[5]), fmaxf(m8[6], m8[7])));
        const bool skip = __all(tmax <= mrun + 8.f);  // defer-max (T13)
        if (!skip) {
            float tq = fmaxf(tmax, __shfl_xor(tmax, 32));
            float mnew = fmaxf(mrun, tq);
            float al = __builtin_amdgcn_exp2f(mrun - mnew);
            lrun *= al;
#pragma unroll
            for (int rr = 0; rr < 16; ++rr) { o0[rr] *= al; o1[rr] *= al; }
            mrun = mnew;
        }
#pragma unroll
        for (int rr = 0; rr < 32; ++rr) pp[rr] = __builtin_amdgcn_exp2f(pp[rr] - mrun);
        float s8[8];
#pragma unroll
        for (int i = 0; i < 8; ++i)
            s8[i] = (pp[4 * i] + pp[4 * i + 1]) + (pp[4 * i + 2] + pp[4 * i + 3]);
        float rsum = ((s8[0] + s8[1]) + (s8[2] + s8[3])) + ((s8[4] + s8[5]) + (s8[6] + s8[7]));
        rsum += __shfl_xor(rsum, 32);
        lrun += rsum;

        // P -> B-frags via cvt_pk + permlane32_swap, then PV
        __builtin_amdgcn_s_setprio(1);
#pragma unroll
        for (int cc = 0; cc < 4; ++cc) {
            const int pb = cc * 8;
            unsigned int A0 = cvtpk_bf16(pp[pb + 0], pp[pb + 1]);
            unsigned int A1 = cvtpk_bf16(pp[pb + 2], pp[pb + 3]);
            unsigned int B0 = cvtpk_bf16(pp[pb + 4], pp[pb + 5]);
            unsigned int B1 = cvtpk_bf16(pp[pb + 6], pp[pb + 7]);
            asm("v_permlane32_swap_b32 %0, %1" : "+v"(A0), "+v"(B0));
            asm("v_permlane32_swap_b32 %0, %1" : "+v"(A1), "+v"(B1));
            u32x4_t wvv; wvv[0] = A0; wvv[1] = A1; wvv[2] = B0; wvv[3] = B1;
            bf16x8 pa = __builtin_bit_cast(bf16x8, wvv);
            const int vcol = (32 * cc + 16 * hi) ^ sw;
            bf16x8 v0 = *(const bf16x8*)(lV + l31 * 128 + vcol);
            bf16x8 v1 = *(const bf16x8*)(lV + (l31 + 32) * 128 + vcol);
            o0 = __builtin_amdgcn_mfma_f32_32x32x16_bf16(v0, pa, o0, 0, 0, 0);
            o1 = __builtin_amdgcn_mfma_f32_32x32x16_bf16(v1, pa, o1, 0, 0, 0);
        }
        __builtin_amdgcn_s_setprio(0);
    };

    stage(0, lds);

    for (int tt = 0; tt < nstream; ++tt) {
        const int cur = tt & 1;
        char* lcur = lds + cur * 16384;
        __builtin_amdgcn_s_barrier();  // both waves done reading buf[cur^1]
        if (tt + 1 < nstream) {
            stage((tt + 1) * 64, lds + (cur ^ 1) * 16384);
            WAITVM8;   // tile tt's 8 ops (per wave) complete; tt+1 in flight
        } else {
            WAITVM0;
        }
        __builtin_amdgcn_s_barrier();  // tile tt fully staged (both waves)
        __builtin_amdgcn_sched_barrier(0);

        const int kv0 = tt * 64;
        const char* lK = lcur;
        const char* lV = lcur + 8192;
        const bool dual = (tt <= qb);  // strip A still active (wave-uniform)

        // QK^T (swapped): S^T[kv][q] for A (if active) and B, sharing K frags
        f32x16 sA0 = {}, sA1 = {}, sB0 = {}, sB1 = {};
        __builtin_amdgcn_s_setprio(1);
        if (dual) {
#pragma unroll
            for (int cc = 0; cc < 4; ++cc) {
                bf16x8 k0 = *(const bf16x8*)(lK + l31 * 128 + colx[cc]);
                bf16x8 k1 = *(const bf16x8*)(lK + (l31 + 32) * 128 + colx[cc]);
                sA0 = __builtin_amdgcn_mfma_f32_32x32x16_bf16(k0, qfA[cc], sA0, 0, 0, 0);
                sA1 = __builtin_amdgcn_mfma_f32_32x32x16_bf16(k1, qfA[cc], sA1, 0, 0, 0);
                sB0 = __builtin_amdgcn_mfma_f32_32x32x16_bf16(k0, qfB[cc], sB0, 0, 0, 0);
                sB1 = __builtin_amdgcn_mfma_f32_32x32x16_bf16(k1, qfB[cc], sB1, 0, 0, 0);
            }
        } else {
#pragma unroll
            for (int cc = 0; cc < 4; ++cc) {
                bf16x8 k0 = *(const bf16x8*)(lK + l31 * 128 + colx[cc]);
                bf16x8 k1 = *(const bf16x8*)(lK + (l31 + 32) * 128 + colx[cc]);
                sB0 = __builtin_amdgcn_mfma_f32_32x32x16_bf16(k0, qfB[cc], sB0, 0, 0, 0);
                sB1 = __builtin_amdgcn_mfma_f32_32x32x16_bf16(k1, qfB[cc], sB1, 0, 0, 0);
            }
        }
        __builtin_amdgcn_s_setprio(0);

        if (dual)
            process(sA0, sA1, qA, tt == qb, kv0, mA, lA, oA0, oA1, lV);
        process(sB0, sB1, qB, tt == nstream - 1, kv0, mB, lB, oB0, oB1, lV);
    }

    // epilogue: both strips
    {
        const float inv = 1.f / lA;
        __bf16* orow = Ob + (sbase + q0A + l31) * 1024 + hoff;
#pragma unroll
        for (int rq = 0; rq < 4; ++rq) {
            bf16x4 e0, e1;
#pragma unroll
            for (int jj = 0; jj < 4; ++jj) {
                e0[jj] = (__bf16)(oA0[rq * 4 + jj] * inv);
                e1[jj] = (__bf16)(oA1[rq * 4 + jj] * inv);
            }
            *(bf16x4*)(orow + 4 * hi + 8 * rq) = e0;
            *(bf16x4*)(orow + 32 + 4 * hi + 8 * rq) = e1;
        }
    }
    {
        const float inv = 1.f / lB;
        __bf16* orow = Ob + (sbase + q0B + l31) * 1024 + hoff;
#pragma unroll
        for (int rq = 0; rq < 4; ++rq) {
            bf16x4 e0, e1;
#pragma unroll
            for (int jj = 0; jj < 4; ++jj) {
                e0[jj] = (__bf16)(oB0[rq * 4 + jj] * inv);
                e1[jj] = (__bf16)(oB1[rq * 4 + jj] * inv);
            }
            *(bf16x4*)(orow + 4 * hi + 8 * rq) = e0;
            *(bf16x4*)(orow + 32 + 4 * hi + 8 * rq) = e1;
        }
    }
}

// ---------------------------------------------------------------- launch
extern "C" void kernel_launch(void* const* d_in, const int* in_sizes, int n_in,
                              void* d_out, int out_size, void* d_ws, size_t ws_size,
                              hipStream_t stream) {
    const float* x  = (const float*)d_in[0];
    const float* wq = (const float*)d_in[1];
    const float* wk = (const float*)d_in[2];
    const float* wv = (const float*)d_in[3];
    const float* wo = (const float*)d_in[4];

    char* ws = (char*)d_ws;
    __bf16* xb = (__bf16*)(ws);
    __bf16* wb = (__bf16*)(ws + 16777216);
    __bf16* Qb = (__bf16*)(ws + 25165824);
    __bf16* Kb = (__bf16*)(ws + 41943040);
    __bf16* Vt = (__bf16*)(ws + 58720256);   // [b][h][d][s]
    __bf16* Ob = (__bf16*)(ws + 75497472);

    const float qscale = 0.18033688011112043f;  // (1/sqrt(64)) * log2(e)

    cast_kernel<<<6144, 256, 0, stream>>>(x, wq, wk, wv, wo, xb, wb);
    gemm_qkv_kernel<<<768, 512, 0, stream>>>(xb, wb, Qb, Kb, Vt, qscale);
    attn_kernel<<<1024, 128, 0, stream>>>(Qb, Kb, Vt, Ob);
    gemm_out_kernel<<<256, 512, 0, stream>>>(Ob, wb + 3145728, (float*)d_out);
}

// Round 5
// 174.115 us; speedup vs baseline: 1.1771x; 1.0391x over previous
//
#include <hip/hip_runtime.h>
#include <hip/hip_bf16.h>

// B=4, S=2048, D=1024, H=16, dk=64. M = B*S = 8192.
// All GEMMs: C[m,n] = sum_k A[m,k] * W[n,k]  (W row-major [out][in], "NT")

typedef __bf16 bf16x8 __attribute__((ext_vector_type(8)));
typedef __bf16 bf16x4 __attribute__((ext_vector_type(4)));
typedef float  f32x4  __attribute__((ext_vector_type(4)));
typedef float  f32x16 __attribute__((ext_vector_type(16)));
typedef unsigned int u32x4_t __attribute__((ext_vector_type(4)));

#define GLOBAL_AS __attribute__((address_space(1)))
#define LDS_AS    __attribute__((address_space(3)))

__device__ __forceinline__ void gload16(const void* g, void* l) {
    __builtin_amdgcn_global_load_lds((const GLOBAL_AS void*)g, (LDS_AS void*)l, 16, 0, 0);
}

__device__ __forceinline__ unsigned int cvtpk_bf16(float lo, float hi) {
    unsigned int r;
    asm("v_cvt_pk_bf16_f32 %0, %1, %2" : "=v"(r) : "v"(lo), "v"(hi));
    return r;
}

#define WAITVM8 asm volatile("s_waitcnt vmcnt(8)" ::: "memory")
#define WAITVM0 asm volatile("s_waitcnt vmcnt(0)" ::: "memory")
#define SCHEDB  __builtin_amdgcn_sched_barrier(0)

// ---------------------------------------------------------------- cast kernel
__global__ __launch_bounds__(256) void cast_kernel(
    const float* __restrict__ x, const float* __restrict__ wq,
    const float* __restrict__ wk, const float* __restrict__ wv,
    const float* __restrict__ wo, __bf16* __restrict__ xb, __bf16* __restrict__ wb) {
    int bid = blockIdx.x;
    const float* src; __bf16* dst; int base;
    if (bid < 4096) {
        src = x; dst = xb; base = bid * 2048;
    } else {
        int r = bid - 4096; int wi = r >> 9;
        src = (wi == 0) ? wq : (wi == 1) ? wk : (wi == 2) ? wv : wo;
        dst = wb + wi * 1048576; base = (r & 511) * 2048;
    }
    int idx = base + threadIdx.x * 8;
    float4 a = *(const float4*)(src + idx);
    float4 b = *(const float4*)(src + idx + 4);
    bf16x8 o;
    o[0] = (__bf16)a.x; o[1] = (__bf16)a.y; o[2] = (__bf16)a.z; o[3] = (__bf16)a.w;
    o[4] = (__bf16)b.x; o[5] = (__bf16)b.y; o[6] = (__bf16)b.z; o[7] = (__bf16)b.w;
    *(bf16x8*)(dst + idx) = o;
}

// ---------------------------------------------------------------- fused QKV GEMM v3
// 128x128 tile, BK=64, 256 thr / 4 waves (2x2), wave tile 64x64. Double-buffered
// 64KB LDS -> 2 blocks/CU: cross-block TLP covers vmcnt/barrier stalls that the
// 1-block/CU 128x256 version could not (all 8 waves hit the same wait). Counted
// vmcnt(8) (T4: loads span barriers), XOR-swizzled staging/reads (T2), setprio
// (T5). Grid 1536 = 64 mt x 24 nt, XCD-swizzled (1536 % 8 == 0 -> bijective).
// nt 0-7 -> Qb (scaled, swapped-mfma epi); 8-15 -> Kb; 16-23 -> Vt[b][h][d][s].
__global__ __launch_bounds__(256) void gemm_qkv_kernel(
    const __bf16* __restrict__ A, const __bf16* __restrict__ W,
    __bf16* __restrict__ Qb, __bf16* __restrict__ Kb, __bf16* __restrict__ Vt,
    float qscale) {
    __shared__ __align__(16) char lds[65536];  // 2 bufs x (A 16KB + B 16KB)
    const int t = threadIdx.x;
    const int wid = t >> 6, lane = t & 63;
    const int g = lane >> 4, m = lane & 15;
    const int wm = wid >> 1, wn = wid & 1;
    const int bid = (blockIdx.x & 7) * 192 + (blockIdx.x >> 3);
    const int mt = bid / 24, nt = bid % 24;
    const int m0 = mt * 128, n0 = nt * 128;
    const bool isV = (n0 >= 2048);

    // staging: 4 A-chunks + 4 B-chunks (16B) per thread, pre-swizzled source,
    // linear LDS dest. chunk ci in [0,1024): row = ci>>3 (128 rows x 128B),
    // stored slot (ci&7) holds logical K-chunk (ci&7)^(row&7).
    const __bf16* sA[4]; const __bf16* sB[4]; int dA[4];
#pragma unroll
    for (int i = 0; i < 4; ++i) {
        const int ci = i * 256 + t;
        const int row = ci >> 3;
        const int k8 = (ci & 7) ^ (row & 7);
        sA[i] = A + (size_t)(m0 + row) * 1024 + k8 * 8;
        sB[i] = W + (size_t)(n0 + row) * 1024 + k8 * 8;
        dA[i] = ci * 16;
    }
    auto stage = [&](int kt, char* buf) {
#pragma unroll
        for (int i = 0; i < 4; ++i) gload16(sA[i] + kt * 64, buf + dA[i]);
#pragma unroll
        for (int i = 0; i < 4; ++i) gload16(sB[i] + kt * 64, buf + 16384 + dA[i]);
    };

    // fragment read offsets (swizzle = ((row&7)<<4), row&7 == m&7)
    const int sw = (m & 7) << 4;
    const int offA = (wm * 64 + m) * 128 + ((g << 4) ^ sw);
    const int offB = (wn * 64 + m) * 128 + ((g << 4) ^ sw);

    stage(0, lds);

    f32x4 acc[4][4] = {};
    for (int kt = 0; kt < 16; ++kt) {
        char* cbuf = lds + (kt & 1) * 32768;
        if (kt < 15) {
            stage(kt + 1, lds + ((kt + 1) & 1) * 32768);
            WAITVM8;   // tile kt's 8 ops (this thread) done; kt+1's in flight
        } else {
            WAITVM0;
        }
        SCHEDB;
        __builtin_amdgcn_s_barrier();   // all threads' tile-kt stores landed
        SCHEDB;
        const char* bA = cbuf;
        const char* bB = cbuf + 16384;
        bf16x8 a0[4], b0[4], a1[4], b1[4];
#pragma unroll
        for (int i = 0; i < 4; ++i) {
            a0[i] = *(const bf16x8*)(bA + (offA + i * 2048));
            b0[i] = *(const bf16x8*)(bB + (offB + i * 2048));
            a1[i] = *(const bf16x8*)(bA + ((offA + i * 2048) ^ 64));
            b1[i] = *(const bf16x8*)(bB + ((offB + i * 2048) ^ 64));
        }
        __builtin_amdgcn_s_setprio(1);
        if (isV) {
#pragma unroll
            for (int mi = 0; mi < 4; ++mi)
#pragma unroll
                for (int ni = 0; ni < 4; ++ni)
                    acc[mi][ni] = __builtin_amdgcn_mfma_f32_16x16x32_bf16(a0[mi], b0[ni], acc[mi][ni], 0, 0, 0);
#pragma unroll
            for (int mi = 0; mi < 4; ++mi)
#pragma unroll
                for (int ni = 0; ni < 4; ++ni)
                    acc[mi][ni] = __builtin_amdgcn_mfma_f32_16x16x32_bf16(a1[mi], b1[ni], acc[mi][ni], 0, 0, 0);
        } else {
#pragma unroll
            for (int mi = 0; mi < 4; ++mi)
#pragma unroll
                for (int ni = 0; ni < 4; ++ni)
                    acc[mi][ni] = __builtin_amdgcn_mfma_f32_16x16x32_bf16(b0[ni], a0[mi], acc[mi][ni], 0, 0, 0);
#pragma unroll
            for (int mi = 0; mi < 4; ++mi)
#pragma unroll
                for (int ni = 0; ni < 4; ++ni)
                    acc[mi][ni] = __builtin_amdgcn_mfma_f32_16x16x32_bf16(b1[ni], a1[mi], acc[mi][ni], 0, 0, 0);
        }
        __builtin_amdgcn_s_setprio(0);
        if (kt < 15) {
            SCHEDB;
            __builtin_amdgcn_s_barrier();  // WAR: readers of buf (kt+1)&1 target done
            SCHEDB;
        }
    }

    if (isV) {
        // normal order: acc[mi][ni][j] = C[s = m0+wm*64+mi*16+4g+j][n = n0v+wn*64+ni*16+m]
        const int bb = m0 >> 11;
        const int sb = (m0 & 2047) + wm * 64 + 4 * g;
        const int hbase = ((n0 - 2048) >> 6) + wn;
#pragma unroll
        for (int mi = 0; mi < 4; ++mi)
#pragma unroll
            for (int ni = 0; ni < 4; ++ni) {
                const int d = ni * 16 + m;
                bf16x4 pk;
                pk[0] = (__bf16)(acc[mi][ni][0]); pk[1] = (__bf16)(acc[mi][ni][1]);
                pk[2] = (__bf16)(acc[mi][ni][2]); pk[3] = (__bf16)(acc[mi][ni][3]);
                *(bf16x4*)(Vt + ((size_t)(bb * 16 + hbase) * 64 + d) * 2048 + sb + mi * 16) = pk;
            }
    } else {
        // swapped order: acc[mi][ni][j] = C[row = m0+wm*64+mi*16+m][col = cb+ni*16+j]
        __bf16* C = (n0 < 1024) ? Qb : Kb;
        const float sc = (n0 < 1024) ? qscale : 1.f;
        const int cb = (n0 & 1023) + wn * 64 + 4 * g;
        const int row = m0 + wm * 64 + m;
#pragma unroll
        for (int mi = 0; mi < 4; ++mi)
#pragma unroll
            for (int ni = 0; ni < 4; ++ni) {
                bf16x4 pk;
                pk[0] = (__bf16)(acc[mi][ni][0] * sc); pk[1] = (__bf16)(acc[mi][ni][1] * sc);
                pk[2] = (__bf16)(acc[mi][ni][2] * sc); pk[3] = (__bf16)(acc[mi][ni][3] * sc);
                *(bf16x4*)(C + (size_t)(row + mi * 16) * 1024 + cb + ni * 16) = pk;
            }
    }
}

// ---------------------------------------------------------------- output GEMM (f32)
// Same 128x128/BK64 double-buffered 2-blocks/CU structure. Grid 512 = 64 mt x 8 nt.
__global__ __launch_bounds__(256) void gemm_out_kernel(
    const __bf16* __restrict__ A, const __bf16* __restrict__ W, float* __restrict__ out) {
    __shared__ __align__(16) char lds[65536];
    const int t = threadIdx.x;
    const int wid = t >> 6, lane = t & 63;
    const int g = lane >> 4, m = lane & 15;
    const int wm = wid >> 1, wn = wid & 1;
    const int bid = (blockIdx.x & 7) * 64 + (blockIdx.x >> 3);
    const int mt = bid >> 3, nt = bid & 7;
    const int m0 = mt * 128, n0 = nt * 128;

    const __bf16* sA[4]; const __bf16* sB[4]; int dA[4];
#pragma unroll
    for (int i = 0; i < 4; ++i) {
        const int ci = i * 256 + t;
        const int row = ci >> 3;
        const int k8 = (ci & 7) ^ (row & 7);
        sA[i] = A + (size_t)(m0 + row) * 1024 + k8 * 8;
        sB[i] = W + (size_t)(n0 + row) * 1024 + k8 * 8;
        dA[i] = ci * 16;
    }
    auto stage = [&](int kt, char* buf) {
#pragma unroll
        for (int i = 0; i < 4; ++i) gload16(sA[i] + kt * 64, buf + dA[i]);
#pragma unroll
        for (int i = 0; i < 4; ++i) gload16(sB[i] + kt * 64, buf + 16384 + dA[i]);
    };

    const int sw = (m & 7) << 4;
    const int offA = (wm * 64 + m) * 128 + ((g << 4) ^ sw);
    const int offB = (wn * 64 + m) * 128 + ((g << 4) ^ sw);

    stage(0, lds);

    f32x4 acc[4][4] = {};
    for (int kt = 0; kt < 16; ++kt) {
        char* cbuf = lds + (kt & 1) * 32768;
        if (kt < 15) {
            stage(kt + 1, lds + ((kt + 1) & 1) * 32768);
            WAITVM8;
        } else {
            WAITVM0;
        }
        SCHEDB;
        __builtin_amdgcn_s_barrier();
        SCHEDB;
        const char* bA = cbuf;
        const char* bB = cbuf + 16384;
        bf16x8 a0[4], b0[4], a1[4], b1[4];
#pragma unroll
        for (int i = 0; i < 4; ++i) {
            a0[i] = *(const bf16x8*)(bA + (offA + i * 2048));
            b0[i] = *(const bf16x8*)(bB + (offB + i * 2048));
            a1[i] = *(const bf16x8*)(bA + ((offA + i * 2048) ^ 64));
            b1[i] = *(const bf16x8*)(bB + ((offB + i * 2048) ^ 64));
        }
        __builtin_amdgcn_s_setprio(1);
#pragma unroll
        for (int mi = 0; mi < 4; ++mi)
#pragma unroll
            for (int ni = 0; ni < 4; ++ni)
                acc[mi][ni] = __builtin_amdgcn_mfma_f32_16x16x32_bf16(b0[ni], a0[mi], acc[mi][ni], 0, 0, 0);
#pragma unroll
        for (int mi = 0; mi < 4; ++mi)
#pragma unroll
            for (int ni = 0; ni < 4; ++ni)
                acc[mi][ni] = __builtin_amdgcn_mfma_f32_16x16x32_bf16(b1[ni], a1[mi], acc[mi][ni], 0, 0, 0);
        __builtin_amdgcn_s_setprio(0);
        if (kt < 15) {
            SCHEDB;
            __builtin_amdgcn_s_barrier();
            SCHEDB;
        }
    }

    const int row = m0 + wm * 64 + m;
    const int col = n0 + wn * 64 + 4 * g;
#pragma unroll
    for (int mi = 0; mi < 4; ++mi)
#pragma unroll
        for (int ni = 0; ni < 4; ++ni)
            *(f32x4*)(out + (size_t)(row + mi * 16) * 1024 + col + ni * 16) = acc[mi][ni];
}

// ---------------------------------------------------------------- flash attention v8
// Round-1 skeleton (2 waves/block, 1024 blocks, XCD-local bh map, balanced pairing)
// with the two phases FUSED over one shared kv stream: block (bh,qb) runs strips
// A=qb and B=31-qb over tiles 0..(31-qb); A participates while tt<=qb. Work stays
// exactly 33 tile-units/block (balanced), staging drops to 32-qb tiles, and dual
// tiles give the wave two independent QK^T->softmax->PV chains to interleave
// (intra-wave ILP; grid parallelism is capped at 2 waves/SIMD). K frags read from
// LDS once, feed both strips. (128,2) caps VGPR at 256 = guaranteed 2 waves/SIMD.
__global__ __launch_bounds__(128, 2) void attn_kernel(
    const __bf16* __restrict__ Qb, const __bf16* __restrict__ Kb,
    const __bf16* __restrict__ Vt, __bf16* __restrict__ Ob) {
    __shared__ __align__(16) char lds[32768];  // 2 bufs x (K 8KB + V 8KB)
    const int t = threadIdx.x;
    const int w = t >> 6, lane = t & 63;
    const int l31 = lane & 31, hi = lane >> 5;
    // XCD remap: launch idx x -> qb = (x>>3)&15, bh = (x&7) | ((x>>7)<<3)
    const int qb = (blockIdx.x >> 3) & 15;
    const int bh = (blockIdx.x & 7) | ((blockIdx.x >> 7) << 3);
    const size_t sbase = (size_t)(bh >> 4) * 2048;
    const int hoff = (bh & 15) * 64;

    const char* Kbase = (const char*)Kb + (sbase * 1024 + hoff) * 2;
    const char* Vbase = (const char*)Vt + (size_t)bh * 262144;
    const int srow = lane >> 3;
    const int scol = ((lane & 7) ^ srow) << 4;  // pre-swizzled source slot
    const int sw = (l31 & 7) << 4;              // read-side swizzle
    int colx[4];
#pragma unroll
    for (int i = 0; i < 4; ++i) colx[i] = (32 * i + 16 * hi) ^ sw;

    // stage one K+V tile into buffer (8 gload16 per wave: 4 K-chunks + 4 V-chunks)
    auto stage = [&](int kv0, char* lK) {
        char* lV = lK + 8192;
#pragma unroll
        for (int i = 0; i < 4; ++i) {
            const int chunk = i * 2 + w;
            const int row = chunk * 8 + srow;
            gload16(Kbase + (size_t)(kv0 + row) * 2048 + scol, lK + chunk * 1024);
            gload16(Vbase + (size_t)row * 4096 + (size_t)kv0 * 2 + scol, lV + chunk * 1024);
        }
    };

    const int q0A = qb * 64 + w * 32;
    const int q0B = (31 - qb) * 64 + w * 32;
    const int qA = q0A + l31, qB = q0B + l31;
    const int nstream = 32 - qb;  // tiles 0..nstream-1 cover both strips

    const __bf16* qrowA = Qb + (sbase + q0A + l31) * 1024 + hoff + 8 * hi;
    const __bf16* qrowB = Qb + (sbase + q0B + l31) * 1024 + hoff + 8 * hi;
    bf16x8 qfA[4], qfB[4];
#pragma unroll
    for (int cq = 0; cq < 4; ++cq) {
        qfA[cq] = *(const bf16x8*)(qrowA + 16 * cq);
        qfB[cq] = *(const bf16x8*)(qrowB + 16 * cq);
    }

    f32x16 oA0 = {}, oA1 = {}, oB0 = {}, oB1 = {};
    float mA = -__builtin_inff(), lA = 0.f;
    float mB = -__builtin_inff(), lB = 0.f;

    // softmax + PV for one strip (s0r/s1r = S^T fragments; diag = causal tile)
    auto process = [&](const f32x16& s0r, const f32x16& s1r, int qq, bool diag,
                       int kv0, float& mrun, float& lrun, f32x16& o0, f32x16& o1,
                       const char* lV) {
        float pp[32];
#pragma unroll
        for (int rr = 0; rr < 16; ++rr) { pp[rr] = s0r[rr]; pp[16 + rr] = s1r[rr]; }
        if (diag) {
#pragma unroll
            for (int rr = 0; rr < 16; ++rr) {
                const int kvl = (rr & 3) + 8 * (rr >> 2) + 4 * hi;
                if (kv0 + kvl > qq)      pp[rr]      = -__builtin_inff();
                if (kv0 + 32 + kvl > qq) pp[16 + rr] = -__builtin_inff();
            }
        }
        float m8[8];
#pragma unroll
        for (int i = 0; i < 8; ++i)
            m8[i] = fmaxf(fmaxf(pp[4 * i], pp[4 * i + 1]), fmaxf(pp[4 * i + 2], pp[4 * i + 3]));
        float tmax = fmaxf(fmaxf(fmaxf(m8[0], m8[1]), fmaxf(m8[2], m8[3])),
                           fmaxf(fmaxf(m8[4], m8[5]), fmaxf(m8[6], m8[7])));
        const bool skip = __all(tmax <= mrun + 8.f);  // defer-max (T13)
        if (!skip) {
            float tq = fmaxf(tmax, __shfl_xor(tmax, 32));
            float mnew = fmaxf(mrun, tq);
            float al = __builtin_amdgcn_exp2f(mrun - mnew);
            lrun *= al;
#pragma unroll
            for (int rr = 0; rr < 16; ++rr) { o0[rr] *= al; o1[rr] *= al; }
            mrun = mnew;
        }
#pragma unroll
        for (int rr = 0; rr < 32; ++rr) pp[rr] = __builtin_amdgcn_exp2f(pp[rr] - mrun);
        float s8[8];
#pragma unroll
        for (int i = 0; i < 8; ++i)
            s8[i] = (pp[4 * i] + pp[4 * i + 1]) + (pp[4 * i + 2] + pp[4 * i + 3]);
        float rsum = ((s8[0] + s8[1]) + (s8[2] + s8[3])) + ((s8[4] + s8[5]) + (s8[6] + s8[7]));
        rsum += __shfl_xor(rsum, 32);
        lrun += rsum;

        // P -> B-frags via cvt_pk + permlane32_swap, then PV
        __builtin_amdgcn_s_setprio(1);
#pragma unroll
        for (int cc = 0; cc < 4; ++cc) {
            const int pb = cc * 8;
            unsigned int A0 = cvtpk_bf16(pp[pb + 0], pp[pb + 1]);
            unsigned int A1 = cvtpk_bf16(pp[pb + 2], pp[pb + 3]);
            unsigned int B0 = cvtpk_bf16(pp[pb + 4], pp[pb + 5]);
            unsigned int B1 = cvtpk_bf16(pp[pb + 6], pp[pb + 7]);
            asm("v_permlane32_swap_b32 %0, %1" : "+v"(A0), "+v"(B0));
            asm("v_permlane32_swap_b32 %0, %1" : "+v"(A1), "+v"(B1));
            u32x4_t wvv; wvv[0] = A0; wvv[1] = A1; wvv[2] = B0; wvv[3] = B1;
            bf16x8 pa = __builtin_bit_cast(bf16x8, wvv);
            const int vcol = (32 * cc + 16 * hi) ^ sw;
            bf16x8 v0 = *(const bf16x8*)(lV + l31 * 128 + vcol);
            bf16x8 v1 = *(const bf16x8*)(lV + (l31 + 32) * 128 + vcol);
            o0 = __builtin_amdgcn_mfma_f32_32x32x16_bf16(v0, pa, o0, 0, 0, 0);
            o1 = __builtin_amdgcn_mfma_f32_32x32x16_bf16(v1, pa, o1, 0, 0, 0);
        }
        __builtin_amdgcn_s_setprio(0);
    };

    stage(0, lds);

    for (int tt = 0; tt < nstream; ++tt) {
        const int cur = tt & 1;
        char* lcur = lds + cur * 16384;
        __builtin_amdgcn_s_barrier();  // both waves done reading buf[cur^1]
        if (tt + 1 < nstream) {
            stage((tt + 1) * 64, lds + (cur ^ 1) * 16384);
            WAITVM8;   // tile tt's 8 ops (per wave) complete; tt+1 in flight
        } else {
            WAITVM0;
        }
        __builtin_amdgcn_s_barrier();  // tile tt fully staged (both waves)
        __builtin_amdgcn_sched_barrier(0);

        const int kv0 = tt * 64;
        const char* lK = lcur;
        const char* lV = lcur + 8192;
        const bool dual = (tt <= qb);  // strip A still active (wave-uniform)

        // QK^T (swapped): S^T[kv][q] for A (if active) and B, sharing K frags
        f32x16 sA0 = {}, sA1 = {}, sB0 = {}, sB1 = {};
        __builtin_amdgcn_s_setprio(1);
        if (dual) {
#pragma unroll
            for (int cc = 0; cc < 4; ++cc) {
                bf16x8 k0 = *(const bf16x8*)(lK + l31 * 128 + colx[cc]);
                bf16x8 k1 = *(const bf16x8*)(lK + (l31 + 32) * 128 + colx[cc]);
                sA0 = __builtin_amdgcn_mfma_f32_32x32x16_bf16(k0, qfA[cc], sA0, 0, 0, 0);
                sA1 = __builtin_amdgcn_mfma_f32_32x32x16_bf16(k1, qfA[cc], sA1, 0, 0, 0);
                sB0 = __builtin_amdgcn_mfma_f32_32x32x16_bf16(k0, qfB[cc], sB0, 0, 0, 0);
                sB1 = __builtin_amdgcn_mfma_f32_32x32x16_bf16(k1, qfB[cc], sB1, 0, 0, 0);
            }
        } else {
#pragma unroll
            for (int cc = 0; cc < 4; ++cc) {
                bf16x8 k0 = *(const bf16x8*)(lK + l31 * 128 + colx[cc]);
                bf16x8 k1 = *(const bf16x8*)(lK + (l31 + 32) * 128 + colx[cc]);
                sB0 = __builtin_amdgcn_mfma_f32_32x32x16_bf16(k0, qfB[cc], sB0, 0, 0, 0);
                sB1 = __builtin_amdgcn_mfma_f32_32x32x16_bf16(k1, qfB[cc], sB1, 0, 0, 0);
            }
        }
        __builtin_amdgcn_s_setprio(0);

        if (dual)
            process(sA0, sA1, qA, tt == qb, kv0, mA, lA, oA0, oA1, lV);
        process(sB0, sB1, qB, tt == nstream - 1, kv0, mB, lB, oB0, oB1, lV);
    }

    // epilogue: both strips
    {
        const float inv = 1.f / lA;
        __bf16* orow = Ob + (sbase + q0A + l31) * 1024 + hoff;
#pragma unroll
        for (int rq = 0; rq < 4; ++rq) {
            bf16x4 e0, e1;
#pragma unroll
            for (int jj = 0; jj < 4; ++jj) {
                e0[jj] = (__bf16)(oA0[rq * 4 + jj] * inv);
                e1[jj] = (__bf16)(oA1[rq * 4 + jj] * inv);
            }
            *(bf16x4*)(orow + 4 * hi + 8 * rq) = e0;
            *(bf16x4*)(orow + 32 + 4 * hi + 8 * rq) = e1;
        }
    }
    {
        const float inv = 1.f / lB;
        __bf16* orow = Ob + (sbase + q0B + l31) * 1024 + hoff;
#pragma unroll
        for (int rq = 0; rq < 4; ++rq) {
            bf16x4 e0, e1;
#pragma unroll
            for (int jj = 0; jj < 4; ++jj) {
                e0[jj] = (__bf16)(oB0[rq * 4 + jj] * inv);
                e1[jj] = (__bf16)(oB1[rq * 4 + jj] * inv);
            }
            *(bf16x4*)(orow + 4 * hi + 8 * rq) = e0;
            *(bf16x4*)(orow + 32 + 4 * hi + 8 * rq) = e1;
        }
    }
}

// ---------------------------------------------------------------- launch
extern "C" void kernel_launch(void* const* d_in, const int* in_sizes, int n_in,
                              void* d_out, int out_size, void* d_ws, size_t ws_size,
                              hipStream_t stream) {
    const float* x  = (const float*)d_in[0];
    const float* wq = (const float*)d_in[1];
    const float* wk = (const float*)d_in[2];
    const float* wv = (const float*)d_in[3];
    const float* wo = (const float*)d_in[4];

    char* ws = (char*)d_ws;
    __bf16* xb = (__bf16*)(ws);
    __bf16* wb = (__bf16*)(ws + 16777216);
    __bf16* Qb = (__bf16*)(ws + 25165824);
    __bf16* Kb = (__bf16*)(ws + 41943040);
    __bf16* Vt = (__bf16*)(ws + 58720256);   // [b][h][d][s]
    __bf16* Ob = (__bf16*)(ws + 75497472);

    const float qscale = 0.18033688011112043f;  // (1/sqrt(64)) * log2(e)

    cast_kernel<<<6144, 256, 0, stream>>>(x, wq, wk, wv, wo, xb, wb);
    gemm_qkv_kernel<<<1536, 256, 0, stream>>>(xb, wb, Qb, Kb, Vt, qscale);
    attn_kernel<<<1024, 128, 0, stream>>>(Qb, Kb, Vt, Ob);
    gemm_out_kernel<<<512, 256, 0, stream>>>(Ob, wb + 3145728, (float*)d_out);
}